// Round 10
// baseline (578.286 us; speedup 1.0000x reference)
//
#include <hip/hip_runtime.h>
#include <math.h>

// ---------------------------------------------------------------------------
// VQ-VAE forward, bf16-MFMA. Round 10: wave-per-row coalesced VQ rescore.
// ---------------------------------------------------------------------------

typedef __bf16 bf16x8_t __attribute__((ext_vector_type(8)));
typedef _Float16 f16x8_t __attribute__((ext_vector_type(8)));
typedef float f32x4_t __attribute__((ext_vector_type(4)));
typedef _Float16 h2_t __attribute__((ext_vector_type(2)));

union FragU { uint4 u; bf16x8_t b; };
union Frag16 { uint4 u; f16x8_t h; };

__device__ inline f32x4_t mfma16(bf16x8_t a, bf16x8_t b, f32x4_t c) {
    return __builtin_amdgcn_mfma_f32_16x16x32_bf16(a, b, c, 0, 0, 0);
}
__device__ inline f32x4_t mfma16h(f16x8_t a, f16x8_t b, f32x4_t c) {
    return __builtin_amdgcn_mfma_f32_16x16x32_f16(a, b, c, 0, 0, 0);
}

__device__ inline void gl_lds16(const void* g, void* l) {
    __builtin_amdgcn_global_load_lds((const __attribute__((address_space(1))) void*)g,
                                     (__attribute__((address_space(3))) void*)l, 16, 0, 0);
}

__device__ inline unsigned bf16rne(float f) {
    unsigned u = __float_as_uint(f);
    u += 0x7FFFu + ((u >> 16) & 1u);
    return u >> 16;
}
__device__ inline unsigned pack2(float lo, float hi) {
    return bf16rne(lo) | (bf16rne(hi) << 16);
}
__device__ inline unsigned pack2h(float lo, float hi) {
    union { h2_t h; unsigned u; } r;
    r.h[0] = (_Float16)lo; r.h[1] = (_Float16)hi;
    return r.u;
}
__device__ inline unsigned short f16bits(float v) {
    union { _Float16 h; unsigned short s; } x; x.h = (_Float16)v; return x.s;
}
__device__ inline float f16lo(unsigned u) {
    union { unsigned u; h2_t h; } x; x.u = u; return (float)x.h[0];
}
__device__ inline float f16hi(unsigned u) {
    union { unsigned u; h2_t h; } x; x.u = u; return (float)x.h[1];
}
__device__ inline float bl(unsigned u) { return __uint_as_float(u << 16); }
__device__ inline float bh(unsigned u) { return __uint_as_float(u & 0xffff0000u); }

#if defined(__has_builtin)
#if __has_builtin(__builtin_amdgcn_fdot2)
#define HAS_FDOT2 1
#endif
#endif

__device__ inline float dot2h(unsigned x, unsigned w, float a) {
#ifdef HAS_FDOT2
    union { unsigned u; h2_t h; } ax, bw;
    ax.u = x; bw.u = w;
    return __builtin_amdgcn_fdot2(ax.h, bw.h, a, false);
#else
    union { unsigned u; _Float16 h[2]; } ax, bw;
    ax.u = x; bw.u = w;
    a = fmaf((float)ax.h[0], (float)bw.h[0], a);
    return fmaf((float)ax.h[1], (float)bw.h[1], a);
#endif
}
__device__ inline float dot8(uint4 x, uint4 w, float a) {
    a = dot2h(x.x, w.x, a); a = dot2h(x.y, w.y, a);
    a = dot2h(x.z, w.z, a); a = dot2h(x.w, w.w, a);
    return a;
}

// ---- generic implicit-GEMM conv -------------------------------------------
// OUTM: 0 = bf16 NHWC halo store, 3 = fp16 NHWC halo store.
template<int NR, int KW_, int SW, int CIC, int SPT, int NT, bool PHASED, int OUTM>
__global__ __launch_bounds__(256) void conv_mfma(
    const unsigned short* __restrict__ in, const unsigned short* __restrict__ wp,
    const float* __restrict__ bias, void* __restrict__ outp,
    int Hp, int Wp, int PS, int nchunks, int Cout, int ncog,
    int Hpo, int Wpo, int relu)
{
    constexpr int W_ST = SW * (SPT - 1) + KW_;
    constexpr int SLOTS_PP = CIC / 8;
    constexpr int ROW_SLOTS = W_ST * SLOTS_PP;
    constexpr int SEGS = (ROW_SLOTS + 63) / 64;
    constexpr int KT = NR * KW_;
    constexpr int CSTEPS = CIC / 32;
    __shared__ __align__(16) unsigned short sh[NR * W_ST * CIC];

    int t = threadIdx.x, lane = t & 63, wv = t >> 6;
    int bx = blockIdx.x;
    int ph = 0, pw = 0, owt = bx;
    if (PHASED) { int phs = bx & 3; ph = phs >> 1; pw = phs & 1; owt = bx >> 2; }
    int ohg = blockIdx.y;
    int bz = blockIdx.z; int nb = bz / ncog; int cog = bz % ncog;
    int ow0 = owt * SPT;
    int row0 = SW * ohg + (PHASED ? ph : 0);
    int col0 = SW * ow0 + (PHASED ? pw : 0);
    int coh = wv & 1;
    int sph = wv >> 1;
    int m = lane & 15, g = lane >> 4;

    if (PHASED) wp += (size_t)(ph * 2 + pw) * Cout * KT * CIC;

    f32x4_t acc[2][NT];
#pragma unroll
    for (int a = 0; a < 2; ++a)
#pragma unroll
        for (int u2 = 0; u2 < NT; ++u2) acc[a][u2] = (f32x4_t){0.f, 0.f, 0.f, 0.f};

    for (int ch = 0; ch < nchunks; ++ch) {
        if (ch) __syncthreads();
        for (int u_ = wv; u_ < NR * SEGS; u_ += 4) {
            int r = u_ / SEGS, seg = u_ - r * SEGS;
            int slot = seg * 64 + lane;
            int p = slot / SLOTS_PP;
            int uu = slot & (SLOTS_PP - 1);
            if (p < W_ST) {
                int su = (uu - (p & 7)) & (SLOTS_PP - 1);
                const unsigned short* gsrc = in +
                    (((size_t)nb * Hp + (row0 + r)) * Wp + (col0 + p)) * PS + ch * CIC + su * 8;
                unsigned short* ldst = sh + ((size_t)(r * ROW_SLOTS + seg * 64 + lane)) * 8;
                gl_lds16(gsrc, ldst);
            }
        }
        __syncthreads();
        int sbase = ch * (KT * CSTEPS);
#pragma unroll
        for (int tap = 0; tap < KT; ++tap) {
            const int r_l = tap / KW_, kwp = tap % KW_;
#pragma unroll
            for (int cs = 0; cs < CSTEPS; ++cs) {
                int s = sbase + tap * CSTEPS + cs;
                const uint4* wr = (const uint4*)wp + (size_t)(s * 4 + g) * Cout + cog * 64 + coh * 32 + m;
                FragU a0, a1;
                a0.u = wr[0];
                a1.u = wr[16];
#pragma unroll
                for (int u2 = 0; u2 < NT; ++u2) {
                    int sp_l = sph * (SPT / 2) + u2 * 16 + m;
                    int p = SW * sp_l + kwp;
                    int off = (cs * 32 + g * 8 + ((p & 7) << 3)) & (CIC - 1);
                    FragU bb;
                    bb.u = *(const uint4*)(sh + (size_t)(r_l * W_ST + p) * CIC + off);
                    acc[0][u2] = mfma16(a0.b, bb.b, acc[0][u2]);
                    acc[1][u2] = mfma16(a1.b, bb.b, acc[1][u2]);
                }
            }
        }
    }
#pragma unroll
    for (int a = 0; a < 2; ++a) {
        int co = cog * 64 + coh * 32 + a * 16 + g * 4;
        float4 bv = *(const float4*)(bias + co);
#pragma unroll
        for (int u2 = 0; u2 < NT; ++u2) {
            int ow = ow0 + sph * (SPT / 2) + u2 * 16 + m;
            float v0 = acc[a][u2][0] + bv.x;
            float v1 = acc[a][u2][1] + bv.y;
            float v2 = acc[a][u2][2] + bv.z;
            float v3 = acc[a][u2][3] + bv.w;
            if (relu) {
                v0 = fmaxf(v0, 0.f); v1 = fmaxf(v1, 0.f);
                v2 = fmaxf(v2, 0.f); v3 = fmaxf(v3, 0.f);
            }
            unsigned short* ob = (unsigned short*)outp;
            int oho = PHASED ? 2 * ohg + ph : ohg;
            int owo = PHASED ? 2 * ow + pw : ow;
            uint2 st;
            if constexpr (OUTM == 3) st = (uint2){pack2h(v0, v1), pack2h(v2, v3)};
            else                     st = (uint2){pack2(v0, v1), pack2(v2, v3)};
            *(uint2*)(ob + (((size_t)nb * Hpo + oho + 1) * Wpo + (owo + 1)) * 64
                      + (coh * 32 + a * 16 + g * 4)) = st;
        }
    }
}

// ---- enc4: 3x3 s1 conv 64->512, 128sp x 128co tiles ------------------------
// Output: K-slab fp16 split zH/zL [s(16)][row(32768)][32].
__global__ __launch_bounds__(256) void k_enc4(
    const unsigned short* __restrict__ a3, const unsigned short* __restrict__ wp,
    const float* __restrict__ bias, unsigned short* __restrict__ zH,
    unsigned short* __restrict__ zL)
{
    __shared__ __align__(16) unsigned short sh[16896];   // 4*528*8 = 33792 B = 128*132
    int t = threadIdx.x, lane = t & 63, wv = t >> 6;
    int wc = wv & 1, wr = wv >> 1;
    int m = lane & 15, g = lane >> 4;
    int L = blockIdx.x;
    int xcd = L & 7, j = L >> 3;
    int cog = j & 3;
    int rt = (j >> 2) + xcd * 32;
    int row0 = rt * 128;
    int n = row0 >> 12;
    int oh0 = (row0 & 4095) >> 6;

    const unsigned short* an = a3 + ((size_t)(n * 66 + oh0) * 66) * 64;
    for (int seg = wv; seg < 33; seg += 4) {
        int slot = seg * 64 + lane;
        if (slot < 2112) {
            int r = slot / 528, rest = slot - r * 528;
            int p = rest >> 3, uu = rest & 7;
            int su = (uu - p) & 7;
            gl_lds16(an + ((size_t)(r * 66 + p)) * 64 + su * 8, sh + (size_t)slot * 8);
        }
    }
    f32x4_t acc[4][4];
#pragma unroll
    for (int a = 0; a < 4; ++a)
#pragma unroll
        for (int b = 0; b < 4; ++b) acc[a][b] = (f32x4_t){0.f, 0.f, 0.f, 0.f};
    __syncthreads();

#pragma unroll
    for (int tap = 0; tap < 9; ++tap) {
        const int kh = tap / 3, kwp = tap % 3;
#pragma unroll
        for (int cs = 0; cs < 2; ++cs) {
            int s = tap * 2 + cs;
            const uint4* wr4 = (const uint4*)wp + (size_t)(s * 4 + g) * 512 + cog * 128 + wc * 64 + m;
            FragU A[4];
#pragma unroll
            for (int ci = 0; ci < 4; ++ci) A[ci].u = wr4[ci * 16];
#pragma unroll
            for (int si = 0; si < 4; ++si) {
                int sp_l = wr * 64 + si * 16 + m;
                int r_l = (sp_l >> 6) + kh;
                int px = (sp_l & 63) + kwp;
                int off = (cs * 4 + g + px) & 7;
                FragU B;
                B.u = *(const uint4*)(sh + ((size_t)(r_l * 528 + px * 8 + off)) * 8);
#pragma unroll
                for (int ci = 0; ci < 4; ++ci)
                    acc[ci][si] = mfma16(A[ci].b, B.b, acc[ci][si]);
            }
        }
    }
    float4 bv[4];
#pragma unroll
    for (int ci = 0; ci < 4; ++ci)
        bv[ci] = *(const float4*)(bias + cog * 128 + wc * 64 + ci * 16 + g * 4);

    // H pass via LDS transpose
    __syncthreads();
#pragma unroll
    for (int ci = 0; ci < 4; ++ci) {
#pragma unroll
        for (int si = 0; si < 4; ++si) {
            float v0 = acc[ci][si][0] + bv[ci].x;
            float v1 = acc[ci][si][1] + bv[ci].y;
            float v2 = acc[ci][si][2] + bv[ci].z;
            float v3 = acc[ci][si][3] + bv[ci].w;
            unsigned h0 = pack2h(v0, v1);
            unsigned h1 = pack2h(v2, v3);
            int row = wr * 64 + si * 16 + m;
            int col = wc * 64 + ci * 16 + g * 4;
            *(uint2*)(sh + (size_t)row * 132 + col) = (uint2){h0, h1};
        }
    }
    __syncthreads();
#pragma unroll
    for (int i = 0; i < 8; ++i) {
        int idx = i * 256 + t;
        int row = idx >> 4, c16 = idx & 15;
        uint4 v = *(const uint4*)(sh + (size_t)row * 132 + c16 * 8);
        int col = cog * 128 + c16 * 8;
        int sblk = col >> 5, off = col & 31;
        *(uint4*)(zH + ((size_t)sblk * 32768 + row0 + row) * 32 + off) = v;
    }
    // L pass
    __syncthreads();
#pragma unroll
    for (int ci = 0; ci < 4; ++ci) {
#pragma unroll
        for (int si = 0; si < 4; ++si) {
            float v0 = acc[ci][si][0] + bv[ci].x;
            float v1 = acc[ci][si][1] + bv[ci].y;
            float v2 = acc[ci][si][2] + bv[ci].z;
            float v3 = acc[ci][si][3] + bv[ci].w;
            unsigned h0 = pack2h(v0, v1);
            unsigned h1 = pack2h(v2, v3);
            unsigned l0 = pack2h(v0 - f16lo(h0), v1 - f16hi(h0));
            unsigned l1 = pack2h(v2 - f16lo(h1), v3 - f16hi(h1));
            int row = wr * 64 + si * 16 + m;
            int col = wc * 64 + ci * 16 + g * 4;
            *(uint2*)(sh + (size_t)row * 132 + col) = (uint2){l0, l1};
        }
    }
    __syncthreads();
#pragma unroll
    for (int i = 0; i < 8; ++i) {
        int idx = i * 256 + t;
        int row = idx >> 4, c16 = idx & 15;
        uint4 v = *(const uint4*)(sh + (size_t)row * 132 + c16 * 8);
        int col = cog * 128 + c16 * 8;
        int sblk = col >> 5, off = col & 31;
        *(uint4*)(zL + ((size_t)sblk * 32768 + row0 + row) * 32 + off) = v;
    }
}

// ---- all halo zeroing in one dispatch --------------------------------------
__global__ __launch_bounds__(256) void k_halo_all(
    unsigned short* a1, unsigned short* a2, unsigned short* a3,
    unsigned short* zq, unsigned short* d1)
{
    unsigned short* buf; int Hp, Wp, PS;
    switch (blockIdx.z) {
        case 0: buf = a1; Hp = 258; Wp = 258; PS = 64; break;
        case 1: buf = a2; Hp = 130; Wp = 130; PS = 64; break;
        case 2: buf = a3; Hp = 66; Wp = 66; PS = 64; break;
        case 3: buf = zq; Hp = 66; Wp = 66; PS = 512; break;
        default: buf = d1; Hp = 66; Wp = 66; PS = 64; break;
    }
    int per = 2 * Wp + 2 * (Hp - 2);
    int chunks = PS >> 3;
    int total = per * chunks;
    int n = blockIdx.y;
    for (int i = blockIdx.x * 256 + threadIdx.x; i < total; i += gridDim.x * 256) {
        int pix = i / chunks, c = i - pix * chunks;
        int h, w;
        if (pix < Wp) { h = 0; w = pix; }
        else if (pix < 2 * Wp) { h = Hp - 1; w = pix - Wp; }
        else { int q = pix - 2 * Wp; h = 1 + (q >> 1); w = (q & 1) ? (Wp - 1) : 0; }
        uint4 zz = {0, 0, 0, 0};
        *(uint4*)(buf + (((size_t)n * Hp + h) * Wp + w) * PS + c * 8) = zz;
    }
}

// ---- weight/codebook prep helpers ------------------------------------------
__device__ inline void prep_conv_dev(const float* __restrict__ w,
    unsigned short* __restrict__ o, int Cout, int Cin, int T, int CIC, int idx)
{
    if (idx >= Cout * Cin * T) return;
    int tap = idx % T; int r = idx / T; int ci = r % Cin; int co = r / Cin;
    int chunk = ci / CIC, cil = ci % CIC;
    int k = chunk * (T * CIC) + tap * CIC + cil;
    int s = k >> 5, g = (k >> 3) & 3, j = k & 7;
    o[((size_t)(s * 4 + g) * Cout + co) * 8 + j] = (unsigned short)bf16rne(w[idx]);
}

__device__ inline void prep_wT_dev(const float* __restrict__ w,
    unsigned short* __restrict__ o, int idx)
{
    if (idx >= 65536) return;
    int ci = idx & 63; int r = idx >> 6;
    int jw = r & 1; r >>= 1;
    int jh = r & 1; r >>= 1;
    int co = r & 63; r >>= 6;
    int pw = r & 1; int ph = (r >> 1) & 1;
    int kh = (1 - ph) + 2 * (1 - jh);
    int kw = (1 - pw) + 2 * (1 - jw);
    int k = (jh * 2 + jw) * 64 + ci;
    int s = k >> 5, g = (k >> 3) & 3, j = k & 7;
    o[(size_t)(ph * 2 + pw) * 16384 + ((size_t)(s * 4 + g) * 64 + co) * 8 + j] =
        (unsigned short)bf16rne(w[((ci * 64 + co) * 4 + kh) * 4 + kw]);
}

// ---- all weight/cb/cn2/scal prep in one dispatch: grid (1152, 8) -----------
__global__ __launch_bounds__(256) void k_prep_all(
    const float* __restrict__ enc_w2, const float* __restrict__ enc_w3,
    const float* __restrict__ enc_w4, const float* __restrict__ dec_w1,
    const float* __restrict__ tw1, const float* __restrict__ tw2,
    const float* __restrict__ cb,
    unsigned short* __restrict__ wA2, unsigned short* __restrict__ wA3,
    unsigned short* __restrict__ wB1, unsigned short* __restrict__ wB2,
    unsigned short* __restrict__ wC1, unsigned short* __restrict__ wC2,
    unsigned short* __restrict__ cbF,
    float* __restrict__ cn2, float* __restrict__ scal)
{
    int idx = blockIdx.x * 256 + threadIdx.x;
    switch (blockIdx.y) {
    case 0: prep_conv_dev(enc_w2, wA2, 64, 64, 16, 64, idx); break;
    case 1: prep_conv_dev(enc_w3, wA3, 64, 64, 16, 64, idx); break;
    case 2: prep_conv_dev(enc_w4, wB1, 512, 64, 9, 64, idx); break;
    case 3: prep_conv_dev(dec_w1, wB2, 64, 512, 9, 128, idx); break;
    case 4: prep_wT_dev(tw1, wC1, idx); break;
    case 5: prep_wT_dev(tw2, wC2, idx); break;
    case 6: {
        if (idx < 262144) {
            int c = idx & 511, k = idx >> 9;
            int cblk = k >> 7, kl = k & 127, s = c >> 5, g = (c >> 3) & 3, j = c & 7;
            size_t off = ((((size_t)cblk * 16 + s) * 4 + g) * 128 + kl) * 8 + j;
            cbF[off] = f16bits(cb[idx]);
        }
    } break;
    default: {
        int code = blockIdx.x * 4 + (threadIdx.x >> 6);
        if (code < 512) {
            int l = threadIdx.x & 63;
            float s = 0.f;
#pragma unroll
            for (int i = 0; i < 8; ++i) {
                float v = cb[code * 512 + l + i * 64];
                s = fmaf(v, v, s);
            }
#pragma unroll
            for (int off = 32; off > 0; off >>= 1) s += __shfl_xor(s, off);
            if (l == 0) cn2[code] = 0.5f * s;
        }
        if (blockIdx.x == 0 && threadIdx.x == 0) { scal[0] = 0.f; scal[1] = 0.f; }
    } break;
    }
}

// ---- enc conv1: Cin=1, 4x4 s2 p1, ReLU -> bf16 NHWC padded ----------------
__global__ __launch_bounds__(256) void k_conv1(const float* __restrict__ x,
    const float* __restrict__ w, const float* __restrict__ b, unsigned short* __restrict__ out)
{
    __shared__ float ws[1024];
    __shared__ float bs[64];
    int t = threadIdx.x;
#pragma unroll
    for (int i = 0; i < 4; ++i) ws[t + 256 * i] = w[t + 256 * i];
    if (t < 64) bs[t] = b[t];
    __syncthreads();
    int oh = blockIdx.x;
    int n = blockIdx.y;
    int ow = t;
    const float* xn = x + (size_t)n * 262144;
    float xv[16];
#pragma unroll
    for (int kh = 0; kh < 4; ++kh) {
        int ih = 2 * oh - 1 + kh;
        bool rok = (unsigned)ih < 512u;
        int ihc = min(max(ih, 0), 511);
#pragma unroll
        for (int kw = 0; kw < 4; ++kw) {
            int iw = 2 * ow - 1 + kw;
            bool ok = rok && ((unsigned)iw < 512u);
            int iwc = min(max(iw, 0), 511);
            float v = xn[ihc * 512 + iwc];
            xv[kh * 4 + kw] = ok ? v : 0.f;
        }
    }
    unsigned short* on = out + (((size_t)n * 258 + oh + 1) * 258 + (ow + 1)) * 64;
    unsigned uo[32];
#pragma unroll
    for (int co2 = 0; co2 < 32; ++co2) {
        float a0 = bs[2 * co2], a1 = bs[2 * co2 + 1];
#pragma unroll
        for (int q = 0; q < 16; ++q) {
            a0 = fmaf(xv[q], ws[(2 * co2) * 16 + q], a0);
            a1 = fmaf(xv[q], ws[(2 * co2 + 1) * 16 + q], a1);
        }
        uo[co2] = pack2(fmaxf(a0, 0.f), fmaxf(a1, 0.f));
    }
#pragma unroll
    for (int i = 0; i < 8; ++i) {
        uint4 st = {uo[4 * i], uo[4 * i + 1], uo[4 * i + 2], uo[4 * i + 3]};
        *(uint4*)(on + i * 8) = st;
    }
}

__device__ inline bool better_sc(float av, int ai, float bv, int bi) {
    return av > bv || (av == bv && ai < bi);
}

// ---- VQ approx GEMM pass-1: fp16 single-term, top-2 per 128-code block -----
__global__ __launch_bounds__(256) void k_vqgemm(
    const unsigned short* __restrict__ zH, const unsigned short* __restrict__ cbF,
    const float* __restrict__ cn2, int* __restrict__ candI)
{
    __shared__ __align__(16) unsigned short shA[10240];  // 2 steps x 128 rows x 40
    __shared__ float tV[2][128][2];
    __shared__ int   tI[2][128][2];
    int t = threadIdx.x, lane = t & 63, wv = t >> 6;
    int wc = wv & 1, wr = wv >> 1;
    int m = lane & 15, g = lane >> 4;
    int L = blockIdx.x;
    int xcd = L & 7, kk = L >> 3;
    int cblk = kk & 3;
    int row0 = ((kk >> 2) + xcd * 32) * 128;

    f32x4_t acc[4][4];
#pragma unroll
    for (int a = 0; a < 4; ++a)
#pragma unroll
        for (int b = 0; b < 4; ++b) acc[a][b] = (f32x4_t){0.f, 0.f, 0.f, 0.f};

    const uint4* bF = (const uint4*)cbF + (size_t)cblk * 8192;

    for (int c = 0; c < 8; ++c) {
        if (c) __syncthreads();
        for (int q = t; q < 1280; q += 256) {
            int ss = q / 640, rest = q - ss * 640;
            int r = rest / 5, seg = rest - r * 5;
            int s = c * 2 + ss;
            gl_lds16(zH + ((size_t)s * 32768 + row0 + r) * 32 + (seg & 3) * 8,
                     shA + (size_t)q * 8);
        }
        __syncthreads();
#pragma unroll
        for (int ss = 0; ss < 2; ++ss) {
            int s = c * 2 + ss;
            Frag16 B[4];
#pragma unroll
            for (int ni = 0; ni < 4; ++ni)
                B[ni].u = bF[(s * 4 + g) * 128 + wc * 64 + ni * 16 + m];
#pragma unroll
            for (int mi = 0; mi < 4; ++mi) {
                Frag16 A;
                A.u = *(const uint4*)(shA + (size_t)(ss * 5120 + (wr * 64 + mi * 16 + m) * 40 + g * 8));
#pragma unroll
                for (int ni = 0; ni < 4; ++ni)
                    acc[mi][ni] = mfma16h(A.h, B[ni].h, acc[mi][ni]);
            }
        }
    }
    float c2[4];
#pragma unroll
    for (int ni = 0; ni < 4; ++ni) c2[ni] = cn2[cblk * 128 + wc * 64 + ni * 16 + m];
#pragma unroll
    for (int mi = 0; mi < 4; ++mi) {
#pragma unroll
        for (int r = 0; r < 4; ++r) {
            float v1 = -3e38f, v2 = -3e38f; int i1 = 0, i2 = 0;
#pragma unroll
            for (int ni = 0; ni < 4; ++ni) {
                float v = acc[mi][ni][r] - c2[ni];
                int ix = cblk * 128 + wc * 64 + ni * 16 + m;
                if (better_sc(v, ix, v1, i1)) { v2 = v1; i2 = i1; v1 = v; i1 = ix; }
                else if (better_sc(v, ix, v2, i2)) { v2 = v; i2 = ix; }
            }
#pragma unroll
            for (int off = 1; off < 16; off <<= 1) {
                float o1 = __shfl_xor(v1, off); int oi1 = __shfl_xor(i1, off);
                float o2 = __shfl_xor(v2, off); int oi2 = __shfl_xor(i2, off);
                if (better_sc(o1, oi1, v1, i1)) {
                    float nv2; int ni2;
                    if (better_sc(v1, i1, o2, oi2)) { nv2 = v1; ni2 = i1; }
                    else { nv2 = o2; ni2 = oi2; }
                    v1 = o1; i1 = oi1; v2 = nv2; i2 = ni2;
                } else if (better_sc(o1, oi1, v2, i2)) { v2 = o1; i2 = oi1; }
            }
            if (m == 0) {
                int row = wr * 64 + mi * 16 + g * 4 + r;
                tV[wc][row][0] = v1; tI[wc][row][0] = i1;
                tV[wc][row][1] = v2; tI[wc][row][1] = i2;
            }
        }
    }
    __syncthreads();
    if (t < 128) {
        float v1 = tV[0][t][0], v2 = tV[0][t][1];
        int i1 = tI[0][t][0], i2 = tI[0][t][1];
        float o1 = tV[1][t][0], o2 = tV[1][t][1];
        int oi1 = tI[1][t][0], oi2 = tI[1][t][1];
        if (better_sc(o1, oi1, v1, i1)) {
            float nv2; int ni2;
            if (better_sc(v1, i1, o2, oi2)) { nv2 = v1; ni2 = i1; }
            else { nv2 = o2; ni2 = oi2; }
            v1 = o1; i1 = oi1; v2 = nv2; i2 = ni2;
        } else if (better_sc(o1, oi1, v2, i2)) { v2 = o1; i2 = oi1; }
        candI[((size_t)cblk * 2 + 0) * 32768 + row0 + t] = i1;
        candI[((size_t)cblk * 2 + 1) * 32768 + row0 + t] = i2;
    }
}

// ---- VQ pass-2: wave-per-row exact fp32 rescore, coalesced cb reads --------
__global__ __launch_bounds__(256) void k_vqfinal(
    const unsigned short* __restrict__ zH, const unsigned short* __restrict__ zL,
    const float* __restrict__ cb, const int* __restrict__ candI,
    int* __restrict__ vidx, float* __restrict__ dsum)
{
    __shared__ float redd[4];
    int t = threadIdx.x, lane = t & 63, wv = t >> 6;
    int row = blockIdx.x * 4 + wv;
    // lane owns channels lane*8 .. lane*8+7 (slab = lane>>2, offset (lane&3)*8)
    size_t zoff = ((size_t)(lane >> 2) * 32768 + row) * 32 + (lane & 3) * 8;
    uint4 hu = *(const uint4*)(zH + zoff);
    uint4 lu = *(const uint4*)(zL + zoff);
    float z0 = f16lo(hu.x) + f16lo(lu.x);
    float z1 = f16hi(hu.x) + f16hi(lu.x);
    float z2 = f16lo(hu.y) + f16lo(lu.y);
    float z3 = f16hi(hu.y) + f16hi(lu.y);
    float z4 = f16lo(hu.z) + f16lo(lu.z);
    float z5 = f16hi(hu.z) + f16hi(lu.z);
    float z6 = f16lo(hu.w) + f16lo(lu.w);
    float z7 = f16hi(hu.w) + f16hi(lu.w);
    int mycand = (lane < 8) ? candI[(size_t)lane * 32768 + row] : 0;
    int cands[8];
    float d[8];
#pragma unroll
    for (int s = 0; s < 8; ++s) cands[s] = __shfl(mycand, s);
#pragma unroll
    for (int s = 0; s < 8; ++s) {
        const float* cr = cb + (size_t)cands[s] * 512 + lane * 8;
        float4 c0 = *(const float4*)cr;
        float4 c1 = *(const float4*)(cr + 4);
        float e, dd = 0.f;
        e = z0 - c0.x; dd = fmaf(e, e, dd);
        e = z1 - c0.y; dd = fmaf(e, e, dd);
        e = z2 - c0.z; dd = fmaf(e, e, dd);
        e = z3 - c0.w; dd = fmaf(e, e, dd);
        e = z4 - c1.x; dd = fmaf(e, e, dd);
        e = z5 - c1.y; dd = fmaf(e, e, dd);
        e = z6 - c1.z; dd = fmaf(e, e, dd);
        e = z7 - c1.w; dd = fmaf(e, e, dd);
        d[s] = dd;
    }
#pragma unroll
    for (int off = 1; off < 64; off <<= 1) {
#pragma unroll
        for (int s = 0; s < 8; ++s) d[s] += __shfl_xor(d[s], off);
    }
    float bd = d[0]; int bi_ = cands[0];
#pragma unroll
    for (int s = 1; s < 8; ++s) {
        if (d[s] < bd || (d[s] == bd && cands[s] < bi_)) { bd = d[s]; bi_ = cands[s]; }
    }
    if (lane == 0) { vidx[row] = bi_; redd[wv] = bd; }
    __syncthreads();
    if (t == 0) atomicAdd(dsum, redd[0] + redd[1] + redd[2] + redd[3]);
}

// ---- gather z_q -> padded NHWC bf16 [8,66,66,512] --------------------------
__global__ __launch_bounds__(256) void k_gather(const int* __restrict__ idx,
    const float* __restrict__ cb, unsigned short* __restrict__ zq)
{
    int t = threadIdx.x;
    int sp = blockIdx.x * 4 + (t >> 6);
    int lane = t & 63;
    int k = idx[sp];
    int n = sp >> 12, hw = sp & 4095, h = hw >> 6, w = hw & 63;
    const float* src = cb + (size_t)k * 512 + lane * 8;
    unsigned short* dst = zq + (((size_t)n * 66 + h + 1) * 66 + (w + 1)) * 512 + lane * 8;
    float4 v0 = *(const float4*)src, v1 = *(const float4*)(src + 4);
    uint4 st = {pack2(v0.x, v0.y), pack2(v0.z, v0.w), pack2(v1.x, v1.y), pack2(v1.z, v1.w)};
    *(uint4*)dst = st;
}

// ---- final conv-transpose 64 -> 1, sigmoid (LDS-staged, fp16 dot2) ---------
__global__ __launch_bounds__(256) void k_convt_final2(const unsigned short* __restrict__ xp,
    const float* __restrict__ w, const float* __restrict__ b, float* __restrict__ out)
{
    __shared__ __align__(16) unsigned short shx[3 * 1040 * 8];  // fp16 bits
    __shared__ __align__(16) unsigned wp[16][32];               // fp16 pairs [tap][c2]
    int t = threadIdx.x, lane = t & 63, wv = t >> 6;
    int bx = blockIdx.x, q = blockIdx.y, n = blockIdx.z;
    int colbase = bx * 128;
#pragma unroll
    for (int i = 0; i < 2; ++i) {
        int qq = t + i * 256;
        int tap = qq >> 5, c2 = qq & 31;
        wp[tap][c2] = pack2h(w[(2 * c2) * 16 + tap], w[(2 * c2 + 1) * 16 + tap]);
    }
    const unsigned short* an = xp + (size_t)n * 258 * 258 * 64;
    for (int u_ = wv; u_ < 51; u_ += 4) {
        int r = u_ / 17, seg = u_ % 17;
        int slot = seg * 64 + lane;
        if (slot < 1040) {
            int p = slot >> 3, uu = slot & 7;
            int su = (uu - p) & 7;
            int row = min(2 * q + r, 257);
            const unsigned short* gsrc = an + ((size_t)row * 258 + colbase + p) * 64 + su * 8;
            gl_lds16(gsrc, shx + ((size_t)(r * 1040 + slot)) * 8);
        }
    }
    __syncthreads();
    int ow = bx * 256 + t;
    int kwA = (ow + 1) & 1;
    int cA = ((ow + 1) >> 1) + 1 - colbase;
    int cB = cA - 1;
    float b0 = b[0];
    float acc0 = b0, acc1 = b0, acc2 = b0, acc3 = b0;
#pragma unroll
    for (int c8 = 0; c8 < 8; ++c8) {
        uint4 xr[3][2];
#pragma unroll
        for (int r = 0; r < 3; ++r) {
            xr[r][0] = *(const uint4*)(shx + (size_t)(r * 1040 + cB * 8 + ((c8 + cB) & 7)) * 8);
            xr[r][1] = *(const uint4*)(shx + (size_t)(r * 1040 + cA * 8 + ((c8 + cA) & 7)) * 8);
        }
        uint4 wA[4], wB[4];
#pragma unroll
        for (int kh = 0; kh < 4; ++kh) {
            wA[kh] = *(const uint4*)&wp[kh * 4 + kwA][c8 * 4];
            wB[kh] = *(const uint4*)&wp[kh * 4 + kwA + 2][c8 * 4];
        }
        acc0 = dot8(xr[1][1], wA[0], acc0); acc0 = dot8(xr[1][0], wB[0], acc0);
        acc0 = dot8(xr[0][1], wA[2], acc0); acc0 = dot8(xr[0][0], wB[2], acc0);
        acc1 = dot8(xr[1][1], wA[1], acc1); acc1 = dot8(xr[1][0], wB[1], acc1);
        acc1 = dot8(xr[0][1], wA[3], acc1); acc1 = dot8(xr[0][0], wB[3], acc1);
        acc2 = dot8(xr[2][1], wA[0], acc2); acc2 = dot8(xr[2][0], wB[0], acc2);
        acc2 = dot8(xr[1][1], wA[2], acc2); acc2 = dot8(xr[1][0], wB[2], acc2);
        acc3 = dot8(xr[2][1], wA[1], acc3); acc3 = dot8(xr[2][0], wB[1], acc3);
        acc3 = dot8(xr[1][1], wA[3], acc3); acc3 = dot8(xr[1][0], wB[3], acc3);
    }
    float accs[4] = {acc0, acc1, acc2, acc3};
    float* on = out + (size_t)n * 262144;
#pragma unroll
    for (int ro = 0; ro < 4; ++ro) {
        int oh = 4 * q - 1 + ro;
        if ((unsigned)oh < 512u)
            on[(size_t)oh * 512 + ow] = 1.0f / (1.0f + __expf(-accs[ro]));
    }
}

// ---- finalize loss: 1.25 * sum(min dist) / N -------------------------------
__global__ void k_loss_final(const float* __restrict__ scal, float* __restrict__ out)
{
    if (threadIdx.x == 0 && blockIdx.x == 0)
        out[0] = 1.25f * scal[0] * (1.0f / 16777216.0f);
}

// ---------------------------------------------------------------------------
extern "C" void kernel_launch(void* const* d_in, const int* in_sizes, int n_in,
                              void* d_out, int out_size, void* d_ws, size_t ws_size,
                              hipStream_t stream)
{
    const float* x      = (const float*)d_in[0];
    const float* enc_w1 = (const float*)d_in[1];
    const float* enc_b1 = (const float*)d_in[2];
    const float* enc_w2 = (const float*)d_in[3];
    const float* enc_b2 = (const float*)d_in[4];
    const float* enc_w3 = (const float*)d_in[5];
    const float* enc_b3 = (const float*)d_in[6];
    const float* enc_w4 = (const float*)d_in[7];
    const float* enc_b4 = (const float*)d_in[8];
    const float* cb     = (const float*)d_in[9];
    const float* dec_w1 = (const float*)d_in[10];
    const float* dec_b1 = (const float*)d_in[11];
    const float* tw1    = (const float*)d_in[12];
    const float* tb1    = (const float*)d_in[13];
    const float* tw2    = (const float*)d_in[14];
    const float* tb2    = (const float*)d_in[15];
    const float* tw3    = (const float*)d_in[16];
    const float* tb3    = (const float*)d_in[17];
    float* out = (float*)d_out;

    unsigned short* a1 = (unsigned short*)d_ws;        // 8*258*258*64
    unsigned short* a2 = a1 + 34076672;                // 8*130*130*64
    unsigned short* a3 = a2 + 8652800;                 // 8*66*66*64
    unsigned short* zH = a3 + 2230272;                 // 16*32768*32 (fp16)
    unsigned short* zL = zH + 16777216;                // 16*32768*32 (fp16)
    unsigned short* zq = zL + 16777216;                // 8*66*66*512
    unsigned short* d1 = zq + 17842176;                // 8*66*66*64
    unsigned short* wA2 = d1 + 2230272;                // 65536
    unsigned short* wA3 = wA2 + 65536;
    unsigned short* wB1 = wA3 + 65536;                 // 294912
    unsigned short* wB2 = wB1 + 294912;                // 294912
    unsigned short* wC1 = wB2 + 294912;                // 65536
    unsigned short* wC2 = wC1 + 65536;                 // 65536
    unsigned short* cbF = wC2 + 65536;                 // 262144 (fp16 frag)
    float* cn2 = (float*)(cbF + 262144);               // 512
    int*   vidx = (int*)(cn2 + 512);                   // 32768
    int*   candI = vidx + 32768;                       // 8*32768
    float* scal = (float*)(candI + 262144);            // 2

    // consolidated halos + preps (also zeroes scal)
    k_halo_all<<<dim3(65, 8, 5), 256, 0, stream>>>(a1, a2, a3, zq, d1);
    k_prep_all<<<dim3(1152, 8), 256, 0, stream>>>(
        enc_w2, enc_w3, enc_w4, dec_w1, tw1, tw2, cb,
        wA2, wA3, wB1, wB2, wC1, wC2, cbF, cn2, scal);

    // pipeline
    k_conv1<<<dim3(256, 8), 256, 0, stream>>>(x, enc_w1, enc_b1, a1);
    conv_mfma<4, 4, 2, 64, 32, 1, false, 0><<<dim3(4, 128, 8), 256, 0, stream>>>(
        a1, wA2, enc_b2, a2, 258, 258, 64, 1, 64, 1, 130, 130, 1);
    conv_mfma<4, 4, 2, 64, 32, 1, false, 0><<<dim3(2, 64, 8), 256, 0, stream>>>(
        a2, wA3, enc_b3, a3, 130, 130, 64, 1, 64, 1, 66, 66, 1);
    k_enc4<<<1024, 256, 0, stream>>>(a3, wB1, enc_b4, zH, zL);
    k_vqgemm<<<1024, 256, 0, stream>>>(zH, cbF, cn2, candI);
    k_vqfinal<<<8192, 256, 0, stream>>>(zH, zL, cb, candI, vidx, scal);
    k_gather<<<8192, 256, 0, stream>>>(vidx, cb, zq);
    conv_mfma<3, 3, 1, 128, 64, 2, false, 0><<<dim3(1, 64, 8), 256, 0, stream>>>(
        zq, wB2, dec_b1, d1, 66, 66, 512, 4, 64, 1, 66, 66, 1);
    conv_mfma<2, 2, 1, 64, 64, 2, true, 0><<<dim3(4, 64, 8), 256, 0, stream>>>(
        d1, wC1, tb1, a2, 66, 66, 64, 1, 64, 1, 130, 130, 1);
    conv_mfma<2, 2, 1, 64, 64, 2, true, 3><<<dim3(8, 128, 8), 256, 0, stream>>>(
        a2, wC2, tb2, a1, 130, 130, 64, 1, 64, 1, 258, 258, 1);
    k_convt_final2<<<dim3(2, 129, 8), 256, 0, stream>>>(a1, tw3, tb3, out);
    k_loss_final<<<1, 64, 0, stream>>>(scal, out + 2097152);
}

// Round 11
// 497.534 us; speedup vs baseline: 1.1623x; 1.1623x over previous
//
#include <hip/hip_runtime.h>
#include <math.h>

// ---------------------------------------------------------------------------
// VQ-VAE forward, bf16-MFMA. Round 11: atomic-free VQ rescore (per-row mind[]
// + single-block loss reduction).
// ---------------------------------------------------------------------------

typedef __bf16 bf16x8_t __attribute__((ext_vector_type(8)));
typedef _Float16 f16x8_t __attribute__((ext_vector_type(8)));
typedef float f32x4_t __attribute__((ext_vector_type(4)));
typedef _Float16 h2_t __attribute__((ext_vector_type(2)));

union FragU { uint4 u; bf16x8_t b; };
union Frag16 { uint4 u; f16x8_t h; };

__device__ inline f32x4_t mfma16(bf16x8_t a, bf16x8_t b, f32x4_t c) {
    return __builtin_amdgcn_mfma_f32_16x16x32_bf16(a, b, c, 0, 0, 0);
}
__device__ inline f32x4_t mfma16h(f16x8_t a, f16x8_t b, f32x4_t c) {
    return __builtin_amdgcn_mfma_f32_16x16x32_f16(a, b, c, 0, 0, 0);
}

__device__ inline void gl_lds16(const void* g, void* l) {
    __builtin_amdgcn_global_load_lds((const __attribute__((address_space(1))) void*)g,
                                     (__attribute__((address_space(3))) void*)l, 16, 0, 0);
}

__device__ inline unsigned bf16rne(float f) {
    unsigned u = __float_as_uint(f);
    u += 0x7FFFu + ((u >> 16) & 1u);
    return u >> 16;
}
__device__ inline unsigned pack2(float lo, float hi) {
    return bf16rne(lo) | (bf16rne(hi) << 16);
}
__device__ inline unsigned pack2h(float lo, float hi) {
    union { h2_t h; unsigned u; } r;
    r.h[0] = (_Float16)lo; r.h[1] = (_Float16)hi;
    return r.u;
}
__device__ inline unsigned short f16bits(float v) {
    union { _Float16 h; unsigned short s; } x; x.h = (_Float16)v; return x.s;
}
__device__ inline float f16lo(unsigned u) {
    union { unsigned u; h2_t h; } x; x.u = u; return (float)x.h[0];
}
__device__ inline float f16hi(unsigned u) {
    union { unsigned u; h2_t h; } x; x.u = u; return (float)x.h[1];
}
__device__ inline float bl(unsigned u) { return __uint_as_float(u << 16); }
__device__ inline float bh(unsigned u) { return __uint_as_float(u & 0xffff0000u); }

#if defined(__has_builtin)
#if __has_builtin(__builtin_amdgcn_fdot2)
#define HAS_FDOT2 1
#endif
#endif

__device__ inline float dot2h(unsigned x, unsigned w, float a) {
#ifdef HAS_FDOT2
    union { unsigned u; h2_t h; } ax, bw;
    ax.u = x; bw.u = w;
    return __builtin_amdgcn_fdot2(ax.h, bw.h, a, false);
#else
    union { unsigned u; _Float16 h[2]; } ax, bw;
    ax.u = x; bw.u = w;
    a = fmaf((float)ax.h[0], (float)bw.h[0], a);
    return fmaf((float)ax.h[1], (float)bw.h[1], a);
#endif
}
__device__ inline float dot8(uint4 x, uint4 w, float a) {
    a = dot2h(x.x, w.x, a); a = dot2h(x.y, w.y, a);
    a = dot2h(x.z, w.z, a); a = dot2h(x.w, w.w, a);
    return a;
}

// ---- generic implicit-GEMM conv -------------------------------------------
// OUTM: 0 = bf16 NHWC halo store, 3 = fp16 NHWC halo store.
template<int NR, int KW_, int SW, int CIC, int SPT, int NT, bool PHASED, int OUTM>
__global__ __launch_bounds__(256) void conv_mfma(
    const unsigned short* __restrict__ in, const unsigned short* __restrict__ wp,
    const float* __restrict__ bias, void* __restrict__ outp,
    int Hp, int Wp, int PS, int nchunks, int Cout, int ncog,
    int Hpo, int Wpo, int relu)
{
    constexpr int W_ST = SW * (SPT - 1) + KW_;
    constexpr int SLOTS_PP = CIC / 8;
    constexpr int ROW_SLOTS = W_ST * SLOTS_PP;
    constexpr int SEGS = (ROW_SLOTS + 63) / 64;
    constexpr int KT = NR * KW_;
    constexpr int CSTEPS = CIC / 32;
    __shared__ __align__(16) unsigned short sh[NR * W_ST * CIC];

    int t = threadIdx.x, lane = t & 63, wv = t >> 6;
    int bx = blockIdx.x;
    int ph = 0, pw = 0, owt = bx;
    if (PHASED) { int phs = bx & 3; ph = phs >> 1; pw = phs & 1; owt = bx >> 2; }
    int ohg = blockIdx.y;
    int bz = blockIdx.z; int nb = bz / ncog; int cog = bz % ncog;
    int ow0 = owt * SPT;
    int row0 = SW * ohg + (PHASED ? ph : 0);
    int col0 = SW * ow0 + (PHASED ? pw : 0);
    int coh = wv & 1;
    int sph = wv >> 1;
    int m = lane & 15, g = lane >> 4;

    if (PHASED) wp += (size_t)(ph * 2 + pw) * Cout * KT * CIC;

    f32x4_t acc[2][NT];
#pragma unroll
    for (int a = 0; a < 2; ++a)
#pragma unroll
        for (int u2 = 0; u2 < NT; ++u2) acc[a][u2] = (f32x4_t){0.f, 0.f, 0.f, 0.f};

    for (int ch = 0; ch < nchunks; ++ch) {
        if (ch) __syncthreads();
        for (int u_ = wv; u_ < NR * SEGS; u_ += 4) {
            int r = u_ / SEGS, seg = u_ - r * SEGS;
            int slot = seg * 64 + lane;
            int p = slot / SLOTS_PP;
            int uu = slot & (SLOTS_PP - 1);
            if (p < W_ST) {
                int su = (uu - (p & 7)) & (SLOTS_PP - 1);
                const unsigned short* gsrc = in +
                    (((size_t)nb * Hp + (row0 + r)) * Wp + (col0 + p)) * PS + ch * CIC + su * 8;
                unsigned short* ldst = sh + ((size_t)(r * ROW_SLOTS + seg * 64 + lane)) * 8;
                gl_lds16(gsrc, ldst);
            }
        }
        __syncthreads();
        int sbase = ch * (KT * CSTEPS);
#pragma unroll
        for (int tap = 0; tap < KT; ++tap) {
            const int r_l = tap / KW_, kwp = tap % KW_;
#pragma unroll
            for (int cs = 0; cs < CSTEPS; ++cs) {
                int s = sbase + tap * CSTEPS + cs;
                const uint4* wr = (const uint4*)wp + (size_t)(s * 4 + g) * Cout + cog * 64 + coh * 32 + m;
                FragU a0, a1;
                a0.u = wr[0];
                a1.u = wr[16];
#pragma unroll
                for (int u2 = 0; u2 < NT; ++u2) {
                    int sp_l = sph * (SPT / 2) + u2 * 16 + m;
                    int p = SW * sp_l + kwp;
                    int off = (cs * 32 + g * 8 + ((p & 7) << 3)) & (CIC - 1);
                    FragU bb;
                    bb.u = *(const uint4*)(sh + (size_t)(r_l * W_ST + p) * CIC + off);
                    acc[0][u2] = mfma16(a0.b, bb.b, acc[0][u2]);
                    acc[1][u2] = mfma16(a1.b, bb.b, acc[1][u2]);
                }
            }
        }
    }
#pragma unroll
    for (int a = 0; a < 2; ++a) {
        int co = cog * 64 + coh * 32 + a * 16 + g * 4;
        float4 bv = *(const float4*)(bias + co);
#pragma unroll
        for (int u2 = 0; u2 < NT; ++u2) {
            int ow = ow0 + sph * (SPT / 2) + u2 * 16 + m;
            float v0 = acc[a][u2][0] + bv.x;
            float v1 = acc[a][u2][1] + bv.y;
            float v2 = acc[a][u2][2] + bv.z;
            float v3 = acc[a][u2][3] + bv.w;
            if (relu) {
                v0 = fmaxf(v0, 0.f); v1 = fmaxf(v1, 0.f);
                v2 = fmaxf(v2, 0.f); v3 = fmaxf(v3, 0.f);
            }
            unsigned short* ob = (unsigned short*)outp;
            int oho = PHASED ? 2 * ohg + ph : ohg;
            int owo = PHASED ? 2 * ow + pw : ow;
            uint2 st;
            if constexpr (OUTM == 3) st = (uint2){pack2h(v0, v1), pack2h(v2, v3)};
            else                     st = (uint2){pack2(v0, v1), pack2(v2, v3)};
            *(uint2*)(ob + (((size_t)nb * Hpo + oho + 1) * Wpo + (owo + 1)) * 64
                      + (coh * 32 + a * 16 + g * 4)) = st;
        }
    }
}

// ---- enc4: 3x3 s1 conv 64->512, 128sp x 128co tiles ------------------------
// Output: K-slab fp16 split zH/zL [s(16)][row(32768)][32].
__global__ __launch_bounds__(256) void k_enc4(
    const unsigned short* __restrict__ a3, const unsigned short* __restrict__ wp,
    const float* __restrict__ bias, unsigned short* __restrict__ zH,
    unsigned short* __restrict__ zL)
{
    __shared__ __align__(16) unsigned short sh[16896];   // 4*528*8 = 33792 B = 128*132
    int t = threadIdx.x, lane = t & 63, wv = t >> 6;
    int wc = wv & 1, wr = wv >> 1;
    int m = lane & 15, g = lane >> 4;
    int L = blockIdx.x;
    int xcd = L & 7, j = L >> 3;
    int cog = j & 3;
    int rt = (j >> 2) + xcd * 32;
    int row0 = rt * 128;
    int n = row0 >> 12;
    int oh0 = (row0 & 4095) >> 6;

    const unsigned short* an = a3 + ((size_t)(n * 66 + oh0) * 66) * 64;
    for (int seg = wv; seg < 33; seg += 4) {
        int slot = seg * 64 + lane;
        if (slot < 2112) {
            int r = slot / 528, rest = slot - r * 528;
            int p = rest >> 3, uu = rest & 7;
            int su = (uu - p) & 7;
            gl_lds16(an + ((size_t)(r * 66 + p)) * 64 + su * 8, sh + (size_t)slot * 8);
        }
    }
    f32x4_t acc[4][4];
#pragma unroll
    for (int a = 0; a < 4; ++a)
#pragma unroll
        for (int b = 0; b < 4; ++b) acc[a][b] = (f32x4_t){0.f, 0.f, 0.f, 0.f};
    __syncthreads();

#pragma unroll
    for (int tap = 0; tap < 9; ++tap) {
        const int kh = tap / 3, kwp = tap % 3;
#pragma unroll
        for (int cs = 0; cs < 2; ++cs) {
            int s = tap * 2 + cs;
            const uint4* wr4 = (const uint4*)wp + (size_t)(s * 4 + g) * 512 + cog * 128 + wc * 64 + m;
            FragU A[4];
#pragma unroll
            for (int ci = 0; ci < 4; ++ci) A[ci].u = wr4[ci * 16];
#pragma unroll
            for (int si = 0; si < 4; ++si) {
                int sp_l = wr * 64 + si * 16 + m;
                int r_l = (sp_l >> 6) + kh;
                int px = (sp_l & 63) + kwp;
                int off = (cs * 4 + g + px) & 7;
                FragU B;
                B.u = *(const uint4*)(sh + ((size_t)(r_l * 528 + px * 8 + off)) * 8);
#pragma unroll
                for (int ci = 0; ci < 4; ++ci)
                    acc[ci][si] = mfma16(A[ci].b, B.b, acc[ci][si]);
            }
        }
    }
    float4 bv[4];
#pragma unroll
    for (int ci = 0; ci < 4; ++ci)
        bv[ci] = *(const float4*)(bias + cog * 128 + wc * 64 + ci * 16 + g * 4);

    // H pass via LDS transpose
    __syncthreads();
#pragma unroll
    for (int ci = 0; ci < 4; ++ci) {
#pragma unroll
        for (int si = 0; si < 4; ++si) {
            float v0 = acc[ci][si][0] + bv[ci].x;
            float v1 = acc[ci][si][1] + bv[ci].y;
            float v2 = acc[ci][si][2] + bv[ci].z;
            float v3 = acc[ci][si][3] + bv[ci].w;
            unsigned h0 = pack2h(v0, v1);
            unsigned h1 = pack2h(v2, v3);
            int row = wr * 64 + si * 16 + m;
            int col = wc * 64 + ci * 16 + g * 4;
            *(uint2*)(sh + (size_t)row * 132 + col) = (uint2){h0, h1};
        }
    }
    __syncthreads();
#pragma unroll
    for (int i = 0; i < 8; ++i) {
        int idx = i * 256 + t;
        int row = idx >> 4, c16 = idx & 15;
        uint4 v = *(const uint4*)(sh + (size_t)row * 132 + c16 * 8);
        int col = cog * 128 + c16 * 8;
        int sblk = col >> 5, off = col & 31;
        *(uint4*)(zH + ((size_t)sblk * 32768 + row0 + row) * 32 + off) = v;
    }
    // L pass
    __syncthreads();
#pragma unroll
    for (int ci = 0; ci < 4; ++ci) {
#pragma unroll
        for (int si = 0; si < 4; ++si) {
            float v0 = acc[ci][si][0] + bv[ci].x;
            float v1 = acc[ci][si][1] + bv[ci].y;
            float v2 = acc[ci][si][2] + bv[ci].z;
            float v3 = acc[ci][si][3] + bv[ci].w;
            unsigned h0 = pack2h(v0, v1);
            unsigned h1 = pack2h(v2, v3);
            unsigned l0 = pack2h(v0 - f16lo(h0), v1 - f16hi(h0));
            unsigned l1 = pack2h(v2 - f16lo(h1), v3 - f16hi(h1));
            int row = wr * 64 + si * 16 + m;
            int col = wc * 64 + ci * 16 + g * 4;
            *(uint2*)(sh + (size_t)row * 132 + col) = (uint2){l0, l1};
        }
    }
    __syncthreads();
#pragma unroll
    for (int i = 0; i < 8; ++i) {
        int idx = i * 256 + t;
        int row = idx >> 4, c16 = idx & 15;
        uint4 v = *(const uint4*)(sh + (size_t)row * 132 + c16 * 8);
        int col = cog * 128 + c16 * 8;
        int sblk = col >> 5, off = col & 31;
        *(uint4*)(zL + ((size_t)sblk * 32768 + row0 + row) * 32 + off) = v;
    }
}

// ---- all halo zeroing in one dispatch --------------------------------------
__global__ __launch_bounds__(256) void k_halo_all(
    unsigned short* a1, unsigned short* a2, unsigned short* a3,
    unsigned short* zq, unsigned short* d1)
{
    unsigned short* buf; int Hp, Wp, PS;
    switch (blockIdx.z) {
        case 0: buf = a1; Hp = 258; Wp = 258; PS = 64; break;
        case 1: buf = a2; Hp = 130; Wp = 130; PS = 64; break;
        case 2: buf = a3; Hp = 66; Wp = 66; PS = 64; break;
        case 3: buf = zq; Hp = 66; Wp = 66; PS = 512; break;
        default: buf = d1; Hp = 66; Wp = 66; PS = 64; break;
    }
    int per = 2 * Wp + 2 * (Hp - 2);
    int chunks = PS >> 3;
    int total = per * chunks;
    int n = blockIdx.y;
    for (int i = blockIdx.x * 256 + threadIdx.x; i < total; i += gridDim.x * 256) {
        int pix = i / chunks, c = i - pix * chunks;
        int h, w;
        if (pix < Wp) { h = 0; w = pix; }
        else if (pix < 2 * Wp) { h = Hp - 1; w = pix - Wp; }
        else { int q = pix - 2 * Wp; h = 1 + (q >> 1); w = (q & 1) ? (Wp - 1) : 0; }
        uint4 zz = {0, 0, 0, 0};
        *(uint4*)(buf + (((size_t)n * Hp + h) * Wp + w) * PS + c * 8) = zz;
    }
}

// ---- weight/codebook prep helpers ------------------------------------------
__device__ inline void prep_conv_dev(const float* __restrict__ w,
    unsigned short* __restrict__ o, int Cout, int Cin, int T, int CIC, int idx)
{
    if (idx >= Cout * Cin * T) return;
    int tap = idx % T; int r = idx / T; int ci = r % Cin; int co = r / Cin;
    int chunk = ci / CIC, cil = ci % CIC;
    int k = chunk * (T * CIC) + tap * CIC + cil;
    int s = k >> 5, g = (k >> 3) & 3, j = k & 7;
    o[((size_t)(s * 4 + g) * Cout + co) * 8 + j] = (unsigned short)bf16rne(w[idx]);
}

__device__ inline void prep_wT_dev(const float* __restrict__ w,
    unsigned short* __restrict__ o, int idx)
{
    if (idx >= 65536) return;
    int ci = idx & 63; int r = idx >> 6;
    int jw = r & 1; r >>= 1;
    int jh = r & 1; r >>= 1;
    int co = r & 63; r >>= 6;
    int pw = r & 1; int ph = (r >> 1) & 1;
    int kh = (1 - ph) + 2 * (1 - jh);
    int kw = (1 - pw) + 2 * (1 - jw);
    int k = (jh * 2 + jw) * 64 + ci;
    int s = k >> 5, g = (k >> 3) & 3, j = k & 7;
    o[(size_t)(ph * 2 + pw) * 16384 + ((size_t)(s * 4 + g) * 64 + co) * 8 + j] =
        (unsigned short)bf16rne(w[((ci * 64 + co) * 4 + kh) * 4 + kw]);
}

// ---- all weight/cb/cn2 prep in one dispatch: grid (1152, 8) ----------------
__global__ __launch_bounds__(256) void k_prep_all(
    const float* __restrict__ enc_w2, const float* __restrict__ enc_w3,
    const float* __restrict__ enc_w4, const float* __restrict__ dec_w1,
    const float* __restrict__ tw1, const float* __restrict__ tw2,
    const float* __restrict__ cb,
    unsigned short* __restrict__ wA2, unsigned short* __restrict__ wA3,
    unsigned short* __restrict__ wB1, unsigned short* __restrict__ wB2,
    unsigned short* __restrict__ wC1, unsigned short* __restrict__ wC2,
    unsigned short* __restrict__ cbF,
    float* __restrict__ cn2)
{
    int idx = blockIdx.x * 256 + threadIdx.x;
    switch (blockIdx.y) {
    case 0: prep_conv_dev(enc_w2, wA2, 64, 64, 16, 64, idx); break;
    case 1: prep_conv_dev(enc_w3, wA3, 64, 64, 16, 64, idx); break;
    case 2: prep_conv_dev(enc_w4, wB1, 512, 64, 9, 64, idx); break;
    case 3: prep_conv_dev(dec_w1, wB2, 64, 512, 9, 128, idx); break;
    case 4: prep_wT_dev(tw1, wC1, idx); break;
    case 5: prep_wT_dev(tw2, wC2, idx); break;
    case 6: {
        if (idx < 262144) {
            int c = idx & 511, k = idx >> 9;
            int cblk = k >> 7, kl = k & 127, s = c >> 5, g = (c >> 3) & 3, j = c & 7;
            size_t off = ((((size_t)cblk * 16 + s) * 4 + g) * 128 + kl) * 8 + j;
            cbF[off] = f16bits(cb[idx]);
        }
    } break;
    default: {
        int code = blockIdx.x * 4 + (threadIdx.x >> 6);
        if (code < 512) {
            int l = threadIdx.x & 63;
            float s = 0.f;
#pragma unroll
            for (int i = 0; i < 8; ++i) {
                float v = cb[code * 512 + l + i * 64];
                s = fmaf(v, v, s);
            }
#pragma unroll
            for (int off = 32; off > 0; off >>= 1) s += __shfl_xor(s, off);
            if (l == 0) cn2[code] = 0.5f * s;
        }
    } break;
    }
}

// ---- enc conv1: Cin=1, 4x4 s2 p1, ReLU -> bf16 NHWC padded ----------------
__global__ __launch_bounds__(256) void k_conv1(const float* __restrict__ x,
    const float* __restrict__ w, const float* __restrict__ b, unsigned short* __restrict__ out)
{
    __shared__ float ws[1024];
    __shared__ float bs[64];
    int t = threadIdx.x;
#pragma unroll
    for (int i = 0; i < 4; ++i) ws[t + 256 * i] = w[t + 256 * i];
    if (t < 64) bs[t] = b[t];
    __syncthreads();
    int oh = blockIdx.x;
    int n = blockIdx.y;
    int ow = t;
    const float* xn = x + (size_t)n * 262144;
    float xv[16];
#pragma unroll
    for (int kh = 0; kh < 4; ++kh) {
        int ih = 2 * oh - 1 + kh;
        bool rok = (unsigned)ih < 512u;
        int ihc = min(max(ih, 0), 511);
#pragma unroll
        for (int kw = 0; kw < 4; ++kw) {
            int iw = 2 * ow - 1 + kw;
            bool ok = rok && ((unsigned)iw < 512u);
            int iwc = min(max(iw, 0), 511);
            float v = xn[ihc * 512 + iwc];
            xv[kh * 4 + kw] = ok ? v : 0.f;
        }
    }
    unsigned short* on = out + (((size_t)n * 258 + oh + 1) * 258 + (ow + 1)) * 64;
    unsigned uo[32];
#pragma unroll
    for (int co2 = 0; co2 < 32; ++co2) {
        float a0 = bs[2 * co2], a1 = bs[2 * co2 + 1];
#pragma unroll
        for (int q = 0; q < 16; ++q) {
            a0 = fmaf(xv[q], ws[(2 * co2) * 16 + q], a0);
            a1 = fmaf(xv[q], ws[(2 * co2 + 1) * 16 + q], a1);
        }
        uo[co2] = pack2(fmaxf(a0, 0.f), fmaxf(a1, 0.f));
    }
#pragma unroll
    for (int i = 0; i < 8; ++i) {
        uint4 st = {uo[4 * i], uo[4 * i + 1], uo[4 * i + 2], uo[4 * i + 3]};
        *(uint4*)(on + i * 8) = st;
    }
}

__device__ inline bool better_sc(float av, int ai, float bv, int bi) {
    return av > bv || (av == bv && ai < bi);
}

// ---- VQ approx GEMM pass-1: fp16 single-term, top-2 per 128-code block -----
__global__ __launch_bounds__(256) void k_vqgemm(
    const unsigned short* __restrict__ zH, const unsigned short* __restrict__ cbF,
    const float* __restrict__ cn2, int* __restrict__ candI)
{
    __shared__ __align__(16) unsigned short shA[10240];  // 2 steps x 128 rows x 40
    __shared__ float tV[2][128][2];
    __shared__ int   tI[2][128][2];
    int t = threadIdx.x, lane = t & 63, wv = t >> 6;
    int wc = wv & 1, wr = wv >> 1;
    int m = lane & 15, g = lane >> 4;
    int L = blockIdx.x;
    int xcd = L & 7, kk = L >> 3;
    int cblk = kk & 3;
    int row0 = ((kk >> 2) + xcd * 32) * 128;

    f32x4_t acc[4][4];
#pragma unroll
    for (int a = 0; a < 4; ++a)
#pragma unroll
        for (int b = 0; b < 4; ++b) acc[a][b] = (f32x4_t){0.f, 0.f, 0.f, 0.f};

    const uint4* bF = (const uint4*)cbF + (size_t)cblk * 8192;

    for (int c = 0; c < 8; ++c) {
        if (c) __syncthreads();
        for (int q = t; q < 1280; q += 256) {
            int ss = q / 640, rest = q - ss * 640;
            int r = rest / 5, seg = rest - r * 5;
            int s = c * 2 + ss;
            gl_lds16(zH + ((size_t)s * 32768 + row0 + r) * 32 + (seg & 3) * 8,
                     shA + (size_t)q * 8);
        }
        __syncthreads();
#pragma unroll
        for (int ss = 0; ss < 2; ++ss) {
            int s = c * 2 + ss;
            Frag16 B[4];
#pragma unroll
            for (int ni = 0; ni < 4; ++ni)
                B[ni].u = bF[(s * 4 + g) * 128 + wc * 64 + ni * 16 + m];
#pragma unroll
            for (int mi = 0; mi < 4; ++mi) {
                Frag16 A;
                A.u = *(const uint4*)(shA + (size_t)(ss * 5120 + (wr * 64 + mi * 16 + m) * 40 + g * 8));
#pragma unroll
                for (int ni = 0; ni < 4; ++ni)
                    acc[mi][ni] = mfma16h(A.h, B[ni].h, acc[mi][ni]);
            }
        }
    }
    float c2[4];
#pragma unroll
    for (int ni = 0; ni < 4; ++ni) c2[ni] = cn2[cblk * 128 + wc * 64 + ni * 16 + m];
#pragma unroll
    for (int mi = 0; mi < 4; ++mi) {
#pragma unroll
        for (int r = 0; r < 4; ++r) {
            float v1 = -3e38f, v2 = -3e38f; int i1 = 0, i2 = 0;
#pragma unroll
            for (int ni = 0; ni < 4; ++ni) {
                float v = acc[mi][ni][r] - c2[ni];
                int ix = cblk * 128 + wc * 64 + ni * 16 + m;
                if (better_sc(v, ix, v1, i1)) { v2 = v1; i2 = i1; v1 = v; i1 = ix; }
                else if (better_sc(v, ix, v2, i2)) { v2 = v; i2 = ix; }
            }
#pragma unroll
            for (int off = 1; off < 16; off <<= 1) {
                float o1 = __shfl_xor(v1, off); int oi1 = __shfl_xor(i1, off);
                float o2 = __shfl_xor(v2, off); int oi2 = __shfl_xor(i2, off);
                if (better_sc(o1, oi1, v1, i1)) {
                    float nv2; int ni2;
                    if (better_sc(v1, i1, o2, oi2)) { nv2 = v1; ni2 = i1; }
                    else { nv2 = o2; ni2 = oi2; }
                    v1 = o1; i1 = oi1; v2 = nv2; i2 = ni2;
                } else if (better_sc(o1, oi1, v2, i2)) { v2 = o1; i2 = oi1; }
            }
            if (m == 0) {
                int row = wr * 64 + mi * 16 + g * 4 + r;
                tV[wc][row][0] = v1; tI[wc][row][0] = i1;
                tV[wc][row][1] = v2; tI[wc][row][1] = i2;
            }
        }
    }
    __syncthreads();
    if (t < 128) {
        float v1 = tV[0][t][0], v2 = tV[0][t][1];
        int i1 = tI[0][t][0], i2 = tI[0][t][1];
        float o1 = tV[1][t][0], o2 = tV[1][t][1];
        int oi1 = tI[1][t][0], oi2 = tI[1][t][1];
        if (better_sc(o1, oi1, v1, i1)) {
            float nv2; int ni2;
            if (better_sc(v1, i1, o2, oi2)) { nv2 = v1; ni2 = i1; }
            else { nv2 = o2; ni2 = oi2; }
            v1 = o1; i1 = oi1; v2 = nv2; i2 = ni2;
        } else if (better_sc(o1, oi1, v2, i2)) { v2 = o1; i2 = oi1; }
        candI[((size_t)cblk * 2 + 0) * 32768 + row0 + t] = i1;
        candI[((size_t)cblk * 2 + 1) * 32768 + row0 + t] = i2;
    }
}

// ---- VQ pass-2: wave-per-row exact fp32 rescore, no atomics ----------------
__global__ __launch_bounds__(256) void k_vqfinal(
    const unsigned short* __restrict__ zH, const unsigned short* __restrict__ zL,
    const float* __restrict__ cb, const int* __restrict__ candI,
    int* __restrict__ vidx, float* __restrict__ mind)
{
    int t = threadIdx.x, lane = t & 63, wv = t >> 6;
    int row = blockIdx.x * 4 + wv;
    size_t zoff = ((size_t)(lane >> 2) * 32768 + row) * 32 + (lane & 3) * 8;
    uint4 hu = *(const uint4*)(zH + zoff);
    uint4 lu = *(const uint4*)(zL + zoff);
    float z0 = f16lo(hu.x) + f16lo(lu.x);
    float z1 = f16hi(hu.x) + f16hi(lu.x);
    float z2 = f16lo(hu.y) + f16lo(lu.y);
    float z3 = f16hi(hu.y) + f16hi(lu.y);
    float z4 = f16lo(hu.z) + f16lo(lu.z);
    float z5 = f16hi(hu.z) + f16hi(lu.z);
    float z6 = f16lo(hu.w) + f16lo(lu.w);
    float z7 = f16hi(hu.w) + f16hi(lu.w);
    int mycand = (lane < 8) ? candI[(size_t)lane * 32768 + row] : 0;
    int cands[8];
    float d[8];
#pragma unroll
    for (int s = 0; s < 8; ++s) cands[s] = __shfl(mycand, s);
#pragma unroll
    for (int s = 0; s < 8; ++s) {
        const float* cr = cb + (size_t)cands[s] * 512 + lane * 8;
        float4 c0 = *(const float4*)cr;
        float4 c1 = *(const float4*)(cr + 4);
        float e, dd = 0.f;
        e = z0 - c0.x; dd = fmaf(e, e, dd);
        e = z1 - c0.y; dd = fmaf(e, e, dd);
        e = z2 - c0.z; dd = fmaf(e, e, dd);
        e = z3 - c0.w; dd = fmaf(e, e, dd);
        e = z4 - c1.x; dd = fmaf(e, e, dd);
        e = z5 - c1.y; dd = fmaf(e, e, dd);
        e = z6 - c1.z; dd = fmaf(e, e, dd);
        e = z7 - c1.w; dd = fmaf(e, e, dd);
        d[s] = dd;
    }
#pragma unroll
    for (int off = 1; off < 64; off <<= 1) {
#pragma unroll
        for (int s = 0; s < 8; ++s) d[s] += __shfl_xor(d[s], off);
    }
    float bd = d[0]; int bi_ = cands[0];
#pragma unroll
    for (int s = 1; s < 8; ++s) {
        if (d[s] < bd || (d[s] == bd && cands[s] < bi_)) { bd = d[s]; bi_ = cands[s]; }
    }
    if (lane == 0) { vidx[row] = bi_; mind[row] = bd; }
}

// ---- gather z_q -> padded NHWC bf16 [8,66,66,512] --------------------------
__global__ __launch_bounds__(256) void k_gather(const int* __restrict__ idx,
    const float* __restrict__ cb, unsigned short* __restrict__ zq)
{
    int t = threadIdx.x;
    int sp = blockIdx.x * 4 + (t >> 6);
    int lane = t & 63;
    int k = idx[sp];
    int n = sp >> 12, hw = sp & 4095, h = hw >> 6, w = hw & 63;
    const float* src = cb + (size_t)k * 512 + lane * 8;
    unsigned short* dst = zq + (((size_t)n * 66 + h + 1) * 66 + (w + 1)) * 512 + lane * 8;
    float4 v0 = *(const float4*)src, v1 = *(const float4*)(src + 4);
    uint4 st = {pack2(v0.x, v0.y), pack2(v0.z, v0.w), pack2(v1.x, v1.y), pack2(v1.z, v1.w)};
    *(uint4*)dst = st;
}

// ---- final conv-transpose 64 -> 1, sigmoid (LDS-staged, fp16 dot2) ---------
__global__ __launch_bounds__(256) void k_convt_final2(const unsigned short* __restrict__ xp,
    const float* __restrict__ w, const float* __restrict__ b, float* __restrict__ out)
{
    __shared__ __align__(16) unsigned short shx[3 * 1040 * 8];  // fp16 bits
    __shared__ __align__(16) unsigned wp[16][32];               // fp16 pairs [tap][c2]
    int t = threadIdx.x, lane = t & 63, wv = t >> 6;
    int bx = blockIdx.x, q = blockIdx.y, n = blockIdx.z;
    int colbase = bx * 128;
#pragma unroll
    for (int i = 0; i < 2; ++i) {
        int qq = t + i * 256;
        int tap = qq >> 5, c2 = qq & 31;
        wp[tap][c2] = pack2h(w[(2 * c2) * 16 + tap], w[(2 * c2 + 1) * 16 + tap]);
    }
    const unsigned short* an = xp + (size_t)n * 258 * 258 * 64;
    for (int u_ = wv; u_ < 51; u_ += 4) {
        int r = u_ / 17, seg = u_ % 17;
        int slot = seg * 64 + lane;
        if (slot < 1040) {
            int p = slot >> 3, uu = slot & 7;
            int su = (uu - p) & 7;
            int row = min(2 * q + r, 257);
            const unsigned short* gsrc = an + ((size_t)row * 258 + colbase + p) * 64 + su * 8;
            gl_lds16(gsrc, shx + ((size_t)(r * 1040 + slot)) * 8);
        }
    }
    __syncthreads();
    int ow = bx * 256 + t;
    int kwA = (ow + 1) & 1;
    int cA = ((ow + 1) >> 1) + 1 - colbase;
    int cB = cA - 1;
    float b0 = b[0];
    float acc0 = b0, acc1 = b0, acc2 = b0, acc3 = b0;
#pragma unroll
    for (int c8 = 0; c8 < 8; ++c8) {
        uint4 xr[3][2];
#pragma unroll
        for (int r = 0; r < 3; ++r) {
            xr[r][0] = *(const uint4*)(shx + (size_t)(r * 1040 + cB * 8 + ((c8 + cB) & 7)) * 8);
            xr[r][1] = *(const uint4*)(shx + (size_t)(r * 1040 + cA * 8 + ((c8 + cA) & 7)) * 8);
        }
        uint4 wA[4], wB[4];
#pragma unroll
        for (int kh = 0; kh < 4; ++kh) {
            wA[kh] = *(const uint4*)&wp[kh * 4 + kwA][c8 * 4];
            wB[kh] = *(const uint4*)&wp[kh * 4 + kwA + 2][c8 * 4];
        }
        acc0 = dot8(xr[1][1], wA[0], acc0); acc0 = dot8(xr[1][0], wB[0], acc0);
        acc0 = dot8(xr[0][1], wA[2], acc0); acc0 = dot8(xr[0][0], wB[2], acc0);
        acc1 = dot8(xr[1][1], wA[1], acc1); acc1 = dot8(xr[1][0], wB[1], acc1);
        acc1 = dot8(xr[0][1], wA[3], acc1); acc1 = dot8(xr[0][0], wB[3], acc1);
        acc2 = dot8(xr[2][1], wA[0], acc2); acc2 = dot8(xr[2][0], wB[0], acc2);
        acc2 = dot8(xr[1][1], wA[2], acc2); acc2 = dot8(xr[1][0], wB[2], acc2);
        acc3 = dot8(xr[2][1], wA[1], acc3); acc3 = dot8(xr[2][0], wB[1], acc3);
        acc3 = dot8(xr[1][1], wA[3], acc3); acc3 = dot8(xr[1][0], wB[3], acc3);
    }
    float accs[4] = {acc0, acc1, acc2, acc3};
    float* on = out + (size_t)n * 262144;
#pragma unroll
    for (int ro = 0; ro < 4; ++ro) {
        int oh = 4 * q - 1 + ro;
        if ((unsigned)oh < 512u)
            on[(size_t)oh * 512 + ow] = 1.0f / (1.0f + __expf(-accs[ro]));
    }
}

// ---- finalize loss: single-block reduction over mind[32768] ----------------
__global__ __launch_bounds__(256) void k_loss_final(const float* __restrict__ mind,
    float* __restrict__ out)
{
    __shared__ float redd[4];
    int t = threadIdx.x;
    float s = 0.f;
#pragma unroll 4
    for (int i = 0; i < 32; ++i) {
        float4 v = *(const float4*)(mind + i * 1024 + t * 4);
        s += v.x + v.y + v.z + v.w;
    }
#pragma unroll
    for (int off = 1; off < 64; off <<= 1) s += __shfl_xor(s, off);
    if ((t & 63) == 0) redd[t >> 6] = s;
    __syncthreads();
    if (t == 0)
        out[0] = 1.25f * (redd[0] + redd[1] + redd[2] + redd[3]) * (1.0f / 16777216.0f);
}

// ---------------------------------------------------------------------------
extern "C" void kernel_launch(void* const* d_in, const int* in_sizes, int n_in,
                              void* d_out, int out_size, void* d_ws, size_t ws_size,
                              hipStream_t stream)
{
    const float* x      = (const float*)d_in[0];
    const float* enc_w1 = (const float*)d_in[1];
    const float* enc_b1 = (const float*)d_in[2];
    const float* enc_w2 = (const float*)d_in[3];
    const float* enc_b2 = (const float*)d_in[4];
    const float* enc_w3 = (const float*)d_in[5];
    const float* enc_b3 = (const float*)d_in[6];
    const float* enc_w4 = (const float*)d_in[7];
    const float* enc_b4 = (const float*)d_in[8];
    const float* cb     = (const float*)d_in[9];
    const float* dec_w1 = (const float*)d_in[10];
    const float* dec_b1 = (const float*)d_in[11];
    const float* tw1    = (const float*)d_in[12];
    const float* tb1    = (const float*)d_in[13];
    const float* tw2    = (const float*)d_in[14];
    const float* tb2    = (const float*)d_in[15];
    const float* tw3    = (const float*)d_in[16];
    const float* tb3    = (const float*)d_in[17];
    float* out = (float*)d_out;

    unsigned short* a1 = (unsigned short*)d_ws;        // 8*258*258*64
    unsigned short* a2 = a1 + 34076672;                // 8*130*130*64
    unsigned short* a3 = a2 + 8652800;                 // 8*66*66*64
    unsigned short* zH = a3 + 2230272;                 // 16*32768*32 (fp16)
    unsigned short* zL = zH + 16777216;                // 16*32768*32 (fp16)
    unsigned short* zq = zL + 16777216;                // 8*66*66*512
    unsigned short* d1 = zq + 17842176;                // 8*66*66*64
    unsigned short* wA2 = d1 + 2230272;                // 65536
    unsigned short* wA3 = wA2 + 65536;
    unsigned short* wB1 = wA3 + 65536;                 // 294912
    unsigned short* wB2 = wB1 + 294912;                // 294912
    unsigned short* wC1 = wB2 + 294912;                // 65536
    unsigned short* wC2 = wC1 + 65536;                 // 65536
    unsigned short* cbF = wC2 + 65536;                 // 262144 (fp16 frag)
    float* cn2 = (float*)(cbF + 262144);               // 512
    int*   vidx = (int*)(cn2 + 512);                   // 32768
    int*   candI = vidx + 32768;                       // 8*32768
    float* mind = (float*)(candI + 262144);            // 32768

    // consolidated halos + preps
    k_halo_all<<<dim3(65, 8, 5), 256, 0, stream>>>(a1, a2, a3, zq, d1);
    k_prep_all<<<dim3(1152, 8), 256, 0, stream>>>(
        enc_w2, enc_w3, enc_w4, dec_w1, tw1, tw2, cb,
        wA2, wA3, wB1, wB2, wC1, wC2, cbF, cn2);

    // pipeline
    k_conv1<<<dim3(256, 8), 256, 0, stream>>>(x, enc_w1, enc_b1, a1);
    conv_mfma<4, 4, 2, 64, 32, 1, false, 0><<<dim3(4, 128, 8), 256, 0, stream>>>(
        a1, wA2, enc_b2, a2, 258, 258, 64, 1, 64, 1, 130, 130, 1);
    conv_mfma<4, 4, 2, 64, 32, 1, false, 0><<<dim3(2, 64, 8), 256, 0, stream>>>(
        a2, wA3, enc_b3, a3, 130, 130, 64, 1, 64, 1, 66, 66, 1);
    k_enc4<<<1024, 256, 0, stream>>>(a3, wB1, enc_b4, zH, zL);
    k_vqgemm<<<1024, 256, 0, stream>>>(zH, cbF, cn2, candI);
    k_vqfinal<<<8192, 256, 0, stream>>>(zH, zL, cb, candI, vidx, mind);
    k_gather<<<8192, 256, 0, stream>>>(vidx, cb, zq);
    conv_mfma<3, 3, 1, 128, 64, 2, false, 0><<<dim3(1, 64, 8), 256, 0, stream>>>(
        zq, wB2, dec_b1, d1, 66, 66, 512, 4, 64, 1, 66, 66, 1);
    conv_mfma<2, 2, 1, 64, 64, 2, true, 0><<<dim3(4, 64, 8), 256, 0, stream>>>(
        d1, wC1, tb1, a2, 66, 66, 64, 1, 64, 1, 130, 130, 1);
    conv_mfma<2, 2, 1, 64, 64, 2, true, 3><<<dim3(8, 128, 8), 256, 0, stream>>>(
        a2, wC2, tb2, a1, 130, 130, 64, 1, 64, 1, 258, 258, 1);
    k_convt_final2<<<dim3(2, 129, 8), 256, 0, stream>>>(a1, tw3, tb3, out);
    k_loss_final<<<1, 256, 0, stream>>>(mind, out + 2097152);
}

// Round 12
// 468.861 us; speedup vs baseline: 1.2334x; 1.0612x over previous
//
#include <hip/hip_runtime.h>
#include <math.h>

// ---------------------------------------------------------------------------
// VQ-VAE forward, bf16-MFMA. Round 12: full-row enc2 kernel (8-chain waves),
// phase-fused conv-transpose kernel (16 MFMA : 8 loads per k-step).
// ---------------------------------------------------------------------------

typedef __bf16 bf16x8_t __attribute__((ext_vector_type(8)));
typedef _Float16 f16x8_t __attribute__((ext_vector_type(8)));
typedef float f32x4_t __attribute__((ext_vector_type(4)));
typedef _Float16 h2_t __attribute__((ext_vector_type(2)));

union FragU { uint4 u; bf16x8_t b; };
union Frag16 { uint4 u; f16x8_t h; };

__device__ inline f32x4_t mfma16(bf16x8_t a, bf16x8_t b, f32x4_t c) {
    return __builtin_amdgcn_mfma_f32_16x16x32_bf16(a, b, c, 0, 0, 0);
}
__device__ inline f32x4_t mfma16h(f16x8_t a, f16x8_t b, f32x4_t c) {
    return __builtin_amdgcn_mfma_f32_16x16x32_f16(a, b, c, 0, 0, 0);
}

__device__ inline void gl_lds16(const void* g, void* l) {
    __builtin_amdgcn_global_load_lds((const __attribute__((address_space(1))) void*)g,
                                     (__attribute__((address_space(3))) void*)l, 16, 0, 0);
}

__device__ inline unsigned bf16rne(float f) {
    unsigned u = __float_as_uint(f);
    u += 0x7FFFu + ((u >> 16) & 1u);
    return u >> 16;
}
__device__ inline unsigned pack2(float lo, float hi) {
    return bf16rne(lo) | (bf16rne(hi) << 16);
}
__device__ inline unsigned pack2h(float lo, float hi) {
    union { h2_t h; unsigned u; } r;
    r.h[0] = (_Float16)lo; r.h[1] = (_Float16)hi;
    return r.u;
}
__device__ inline unsigned short f16bits(float v) {
    union { _Float16 h; unsigned short s; } x; x.h = (_Float16)v; return x.s;
}
__device__ inline float f16lo(unsigned u) {
    union { unsigned u; h2_t h; } x; x.u = u; return (float)x.h[0];
}
__device__ inline float f16hi(unsigned u) {
    union { unsigned u; h2_t h; } x; x.u = u; return (float)x.h[1];
}
__device__ inline float bl(unsigned u) { return __uint_as_float(u << 16); }
__device__ inline float bh(unsigned u) { return __uint_as_float(u & 0xffff0000u); }

#if defined(__has_builtin)
#if __has_builtin(__builtin_amdgcn_fdot2)
#define HAS_FDOT2 1
#endif
#endif

__device__ inline float dot2h(unsigned x, unsigned w, float a) {
#ifdef HAS_FDOT2
    union { unsigned u; h2_t h; } ax, bw;
    ax.u = x; bw.u = w;
    return __builtin_amdgcn_fdot2(ax.h, bw.h, a, false);
#else
    union { unsigned u; _Float16 h[2]; } ax, bw;
    ax.u = x; bw.u = w;
    a = fmaf((float)ax.h[0], (float)bw.h[0], a);
    return fmaf((float)ax.h[1], (float)bw.h[1], a);
#endif
}
__device__ inline float dot8(uint4 x, uint4 w, float a) {
    a = dot2h(x.x, w.x, a); a = dot2h(x.y, w.y, a);
    a = dot2h(x.z, w.z, a); a = dot2h(x.w, w.w, a);
    return a;
}

// ---- generic implicit-GEMM conv (enc3, dec1) -------------------------------
template<int NR, int KW_, int SW, int CIC, int SPT, int NT, int OUTM>
__global__ __launch_bounds__(256) void conv_mfma(
    const unsigned short* __restrict__ in, const unsigned short* __restrict__ wp,
    const float* __restrict__ bias, void* __restrict__ outp,
    int Hp, int Wp, int PS, int nchunks, int Cout, int ncog,
    int Hpo, int Wpo, int relu)
{
    constexpr int W_ST = SW * (SPT - 1) + KW_;
    constexpr int SLOTS_PP = CIC / 8;
    constexpr int ROW_SLOTS = W_ST * SLOTS_PP;
    constexpr int SEGS = (ROW_SLOTS + 63) / 64;
    constexpr int KT = NR * KW_;
    constexpr int CSTEPS = CIC / 32;
    __shared__ __align__(16) unsigned short sh[NR * W_ST * CIC];

    int t = threadIdx.x, lane = t & 63, wv = t >> 6;
    int bx = blockIdx.x;
    int owt = bx;
    int ohg = blockIdx.y;
    int bz = blockIdx.z; int nb = bz / ncog; int cog = bz % ncog;
    int ow0 = owt * SPT;
    int row0 = SW * ohg;
    int col0 = SW * ow0;
    int coh = wv & 1;
    int sph = wv >> 1;
    int m = lane & 15, g = lane >> 4;

    f32x4_t acc[2][NT];
#pragma unroll
    for (int a = 0; a < 2; ++a)
#pragma unroll
        for (int u2 = 0; u2 < NT; ++u2) acc[a][u2] = (f32x4_t){0.f, 0.f, 0.f, 0.f};

    for (int ch = 0; ch < nchunks; ++ch) {
        if (ch) __syncthreads();
        for (int u_ = wv; u_ < NR * SEGS; u_ += 4) {
            int r = u_ / SEGS, seg = u_ - r * SEGS;
            int slot = seg * 64 + lane;
            int p = slot / SLOTS_PP;
            int uu = slot & (SLOTS_PP - 1);
            if (p < W_ST) {
                int su = (uu - (p & 7)) & (SLOTS_PP - 1);
                const unsigned short* gsrc = in +
                    (((size_t)nb * Hp + (row0 + r)) * Wp + (col0 + p)) * PS + ch * CIC + su * 8;
                unsigned short* ldst = sh + ((size_t)(r * ROW_SLOTS + seg * 64 + lane)) * 8;
                gl_lds16(gsrc, ldst);
            }
        }
        __syncthreads();
        int sbase = ch * (KT * CSTEPS);
#pragma unroll
        for (int tap = 0; tap < KT; ++tap) {
            const int r_l = tap / KW_, kwp = tap % KW_;
#pragma unroll
            for (int cs = 0; cs < CSTEPS; ++cs) {
                int s = sbase + tap * CSTEPS + cs;
                const uint4* wr = (const uint4*)wp + (size_t)(s * 4 + g) * Cout + cog * 64 + coh * 32 + m;
                FragU a0, a1;
                a0.u = wr[0];
                a1.u = wr[16];
#pragma unroll
                for (int u2 = 0; u2 < NT; ++u2) {
                    int sp_l = sph * (SPT / 2) + u2 * 16 + m;
                    int p = SW * sp_l + kwp;
                    int off = (cs * 32 + g * 8 + ((p & 7) << 3)) & (CIC - 1);
                    FragU bb;
                    bb.u = *(const uint4*)(sh + (size_t)(r_l * W_ST + p) * CIC + off);
                    acc[0][u2] = mfma16(a0.b, bb.b, acc[0][u2]);
                    acc[1][u2] = mfma16(a1.b, bb.b, acc[1][u2]);
                }
            }
        }
    }
#pragma unroll
    for (int a = 0; a < 2; ++a) {
        int co = cog * 64 + coh * 32 + a * 16 + g * 4;
        float4 bv = *(const float4*)(bias + co);
#pragma unroll
        for (int u2 = 0; u2 < NT; ++u2) {
            int ow = ow0 + sph * (SPT / 2) + u2 * 16 + m;
            float v0 = acc[a][u2][0] + bv.x;
            float v1 = acc[a][u2][1] + bv.y;
            float v2 = acc[a][u2][2] + bv.z;
            float v3 = acc[a][u2][3] + bv.w;
            if (relu) {
                v0 = fmaxf(v0, 0.f); v1 = fmaxf(v1, 0.f);
                v2 = fmaxf(v2, 0.f); v3 = fmaxf(v3, 0.f);
            }
            unsigned short* ob = (unsigned short*)outp;
            uint2 st;
            if constexpr (OUTM == 3) st = (uint2){pack2h(v0, v1), pack2h(v2, v3)};
            else                     st = (uint2){pack2(v0, v1), pack2(v2, v3)};
            *(uint2*)(ob + (((size_t)nb * Hpo + ohg + 1) * Wpo + (ow + 1)) * 64
                      + (coh * 32 + a * 16 + g * 4)) = st;
        }
    }
}

// ---- enc2: 4x4 s2 conv 64->64, full-row blocks (64co x 128sp) --------------
// Stage one 258-px input row per kh chunk; wave = 64co x 32sp; 8 MFMA : 6 loads.
__global__ __launch_bounds__(256) void k_enc2w(
    const unsigned short* __restrict__ in, const unsigned short* __restrict__ wp,
    const float* __restrict__ bias, unsigned short* __restrict__ out)
{
    __shared__ __align__(16) unsigned short sh[16512];   // 258 px x 64 ch
    int t = threadIdx.x, lane = t & 63, wv = t >> 6;
    int m = lane & 15, g = lane >> 4;
    int ohg = blockIdx.x, n = blockIdx.y;

    f32x4_t acc[4][2];
#pragma unroll
    for (int a = 0; a < 4; ++a)
#pragma unroll
        for (int u2 = 0; u2 < 2; ++u2) acc[a][u2] = (f32x4_t){0.f, 0.f, 0.f, 0.f};

    const uint4* wp4 = (const uint4*)wp;
#pragma unroll
    for (int kh = 0; kh < 4; ++kh) {
        if (kh) __syncthreads();
        const unsigned short* rowp = in + ((size_t)(n * 258 + 2 * ohg + kh) * 258) * 64;
        for (int q = t; q < 2064; q += 256) {
            int p = q >> 3, uu = q & 7;
            int su = (uu - ((p >> 1) & 7)) & 7;     // stride-2-correct rotation
            gl_lds16(rowp + (size_t)p * 64 + su * 8, sh + (size_t)q * 8);
        }
        __syncthreads();
#pragma unroll
        for (int kwp = 0; kwp < 4; ++kwp) {
#pragma unroll
            for (int cs = 0; cs < 2; ++cs) {
                int s = (kh * 4 + kwp) * 2 + cs;
                const uint4* wr = wp4 + (size_t)(s * 4 + g) * 64 + m;
                FragU A[4];
#pragma unroll
                for (int a = 0; a < 4; ++a) A[a].u = wr[a * 16];
#pragma unroll
                for (int u2 = 0; u2 < 2; ++u2) {
                    int sp_l = wv * 32 + u2 * 16 + m;
                    int p = 2 * sp_l + kwp;
                    int rot = (sp_l + (kwp >> 1)) & 7;
                    int off = (cs * 32 + g * 8 + rot * 8) & 63;
                    FragU B;
                    B.u = *(const uint4*)(sh + (size_t)p * 64 + off);
#pragma unroll
                    for (int a = 0; a < 4; ++a)
                        acc[a][u2] = mfma16(A[a].b, B.b, acc[a][u2]);
                }
            }
        }
    }
#pragma unroll
    for (int a = 0; a < 4; ++a) {
        float4 bv = *(const float4*)(bias + a * 16 + g * 4);
#pragma unroll
        for (int u2 = 0; u2 < 2; ++u2) {
            int ow = wv * 32 + u2 * 16 + m;
            float v0 = fmaxf(acc[a][u2][0] + bv.x, 0.f);
            float v1 = fmaxf(acc[a][u2][1] + bv.y, 0.f);
            float v2 = fmaxf(acc[a][u2][2] + bv.z, 0.f);
            float v3 = fmaxf(acc[a][u2][3] + bv.w, 0.f);
            uint2 st = {pack2(v0, v1), pack2(v2, v3)};
            *(uint2*)(out + ((size_t)(n * 130 + ohg + 1) * 130 + ow + 1) * 64
                      + a * 16 + g * 4) = st;
        }
    }
}

// ---- fused conv-transpose 4x4 s2: all 4 phases in one block ---------------
// Block: output rows {2*ohg, 2*ohg+1} x 128 out-cols x 64 co. Wave = phase.
// Stage 3 input rows x 66 px once; per k-step 4 wt + 4 ds : 16 MFMA.
template<int OUTM>
__global__ __launch_bounds__(256) void k_convtf(
    const unsigned short* __restrict__ in, const unsigned short* __restrict__ wp,
    const float* __restrict__ bias, unsigned short* __restrict__ out,
    int Hpi, int Wpi, int Hpo, int Wpo)
{
    __shared__ __align__(16) unsigned short sh[12672];   // 3 x 66 x 64
    int t = threadIdx.x, lane = t & 63, wv = t >> 6;
    int m = lane & 15, g = lane >> 4;
    int ph = wv >> 1, pw = wv & 1;
    int owt = blockIdx.x, ohg = blockIdx.y, n = blockIdx.z;
    int col0 = owt * 64;

    const unsigned short* an = in + ((size_t)(n * Hpi + ohg) * Wpi + col0) * 64;
    for (int q = t; q < 1584; q += 256) {
        int r = q / 528, rest = q - r * 528;
        int p = rest >> 3, uu = rest & 7;
        int su = (uu - (p & 7)) & 7;
        gl_lds16(an + ((size_t)r * Wpi + p) * 64 + su * 8, sh + (size_t)q * 8);
    }
    f32x4_t acc[4][4];
#pragma unroll
    for (int a = 0; a < 4; ++a)
#pragma unroll
        for (int u2 = 0; u2 < 4; ++u2) acc[a][u2] = (f32x4_t){0.f, 0.f, 0.f, 0.f};
    __syncthreads();

    const uint4* ws4 = (const uint4*)(wp + (size_t)(ph * 2 + pw) * 16384);
#pragma unroll
    for (int jh = 0; jh < 2; ++jh) {
#pragma unroll
        for (int jw = 0; jw < 2; ++jw) {
#pragma unroll
            for (int cs = 0; cs < 2; ++cs) {
                int s = (jh * 2 + jw) * 2 + cs;
                const uint4* wr = ws4 + (size_t)(s * 4 + g) * 64 + m;
                FragU A[4];
#pragma unroll
                for (int a = 0; a < 4; ++a) A[a].u = wr[a * 16];
                int r_l = ph + jh;
#pragma unroll
                for (int u2 = 0; u2 < 4; ++u2) {
                    int p = u2 * 16 + m + pw + jw;
                    int off = (cs * 32 + g * 8 + ((p & 7) << 3)) & 63;
                    FragU B;
                    B.u = *(const uint4*)(sh + (size_t)(r_l * 528 + p * 8) * 8 + off);
#pragma unroll
                    for (int a = 0; a < 4; ++a)
                        acc[a][u2] = mfma16(A[a].b, B.b, acc[a][u2]);
                }
            }
        }
    }
    int oho = 2 * ohg + ph;
#pragma unroll
    for (int a = 0; a < 4; ++a) {
        float4 bv = *(const float4*)(bias + a * 16 + g * 4);
#pragma unroll
        for (int u2 = 0; u2 < 4; ++u2) {
            int owo = 2 * (col0 + u2 * 16 + m) + pw;
            float v0 = fmaxf(acc[a][u2][0] + bv.x, 0.f);
            float v1 = fmaxf(acc[a][u2][1] + bv.y, 0.f);
            float v2 = fmaxf(acc[a][u2][2] + bv.z, 0.f);
            float v3 = fmaxf(acc[a][u2][3] + bv.w, 0.f);
            uint2 st;
            if constexpr (OUTM == 3) st = (uint2){pack2h(v0, v1), pack2h(v2, v3)};
            else                     st = (uint2){pack2(v0, v1), pack2(v2, v3)};
            *(uint2*)(out + ((size_t)(n * Hpo + oho + 1) * Wpo + owo + 1) * 64
                      + a * 16 + g * 4) = st;
        }
    }
}

// ---- enc4: 3x3 s1 conv 64->512, 128sp x 128co tiles ------------------------
__global__ __launch_bounds__(256) void k_enc4(
    const unsigned short* __restrict__ a3, const unsigned short* __restrict__ wp,
    const float* __restrict__ bias, unsigned short* __restrict__ zH,
    unsigned short* __restrict__ zL)
{
    __shared__ __align__(16) unsigned short sh[16896];
    int t = threadIdx.x, lane = t & 63, wv = t >> 6;
    int wc = wv & 1, wr = wv >> 1;
    int m = lane & 15, g = lane >> 4;
    int L = blockIdx.x;
    int xcd = L & 7, j = L >> 3;
    int cog = j & 3;
    int rt = (j >> 2) + xcd * 32;
    int row0 = rt * 128;
    int n = row0 >> 12;
    int oh0 = (row0 & 4095) >> 6;

    const unsigned short* an = a3 + ((size_t)(n * 66 + oh0) * 66) * 64;
    for (int seg = wv; seg < 33; seg += 4) {
        int slot = seg * 64 + lane;
        if (slot < 2112) {
            int r = slot / 528, rest = slot - r * 528;
            int p = rest >> 3, uu = rest & 7;
            int su = (uu - p) & 7;
            gl_lds16(an + ((size_t)(r * 66 + p)) * 64 + su * 8, sh + (size_t)slot * 8);
        }
    }
    f32x4_t acc[4][4];
#pragma unroll
    for (int a = 0; a < 4; ++a)
#pragma unroll
        for (int b = 0; b < 4; ++b) acc[a][b] = (f32x4_t){0.f, 0.f, 0.f, 0.f};
    __syncthreads();

#pragma unroll
    for (int tap = 0; tap < 9; ++tap) {
        const int kh = tap / 3, kwp = tap % 3;
#pragma unroll
        for (int cs = 0; cs < 2; ++cs) {
            int s = tap * 2 + cs;
            const uint4* wr4 = (const uint4*)wp + (size_t)(s * 4 + g) * 512 + cog * 128 + wc * 64 + m;
            FragU A[4];
#pragma unroll
            for (int ci = 0; ci < 4; ++ci) A[ci].u = wr4[ci * 16];
#pragma unroll
            for (int si = 0; si < 4; ++si) {
                int sp_l = wr * 64 + si * 16 + m;
                int r_l = (sp_l >> 6) + kh;
                int px = (sp_l & 63) + kwp;
                int off = (cs * 4 + g + px) & 7;
                FragU B;
                B.u = *(const uint4*)(sh + ((size_t)(r_l * 528 + px * 8 + off)) * 8);
#pragma unroll
                for (int ci = 0; ci < 4; ++ci)
                    acc[ci][si] = mfma16(A[ci].b, B.b, acc[ci][si]);
            }
        }
    }
    float4 bv[4];
#pragma unroll
    for (int ci = 0; ci < 4; ++ci)
        bv[ci] = *(const float4*)(bias + cog * 128 + wc * 64 + ci * 16 + g * 4);

    __syncthreads();
#pragma unroll
    for (int ci = 0; ci < 4; ++ci) {
#pragma unroll
        for (int si = 0; si < 4; ++si) {
            float v0 = acc[ci][si][0] + bv[ci].x;
            float v1 = acc[ci][si][1] + bv[ci].y;
            float v2 = acc[ci][si][2] + bv[ci].z;
            float v3 = acc[ci][si][3] + bv[ci].w;
            unsigned h0 = pack2h(v0, v1);
            unsigned h1 = pack2h(v2, v3);
            int row = wr * 64 + si * 16 + m;
            int col = wc * 64 + ci * 16 + g * 4;
            *(uint2*)(sh + (size_t)row * 132 + col) = (uint2){h0, h1};
        }
    }
    __syncthreads();
#pragma unroll
    for (int i = 0; i < 8; ++i) {
        int idx = i * 256 + t;
        int row = idx >> 4, c16 = idx & 15;
        uint4 v = *(const uint4*)(sh + (size_t)row * 132 + c16 * 8);
        int col = cog * 128 + c16 * 8;
        int sblk = col >> 5, off = col & 31;
        *(uint4*)(zH + ((size_t)sblk * 32768 + row0 + row) * 32 + off) = v;
    }
    __syncthreads();
#pragma unroll
    for (int ci = 0; ci < 4; ++ci) {
#pragma unroll
        for (int si = 0; si < 4; ++si) {
            float v0 = acc[ci][si][0] + bv[ci].x;
            float v1 = acc[ci][si][1] + bv[ci].y;
            float v2 = acc[ci][si][2] + bv[ci].z;
            float v3 = acc[ci][si][3] + bv[ci].w;
            unsigned h0 = pack2h(v0, v1);
            unsigned h1 = pack2h(v2, v3);
            unsigned l0 = pack2h(v0 - f16lo(h0), v1 - f16hi(h0));
            unsigned l1 = pack2h(v2 - f16lo(h1), v3 - f16hi(h1));
            int row = wr * 64 + si * 16 + m;
            int col = wc * 64 + ci * 16 + g * 4;
            *(uint2*)(sh + (size_t)row * 132 + col) = (uint2){l0, l1};
        }
    }
    __syncthreads();
#pragma unroll
    for (int i = 0; i < 8; ++i) {
        int idx = i * 256 + t;
        int row = idx >> 4, c16 = idx & 15;
        uint4 v = *(const uint4*)(sh + (size_t)row * 132 + c16 * 8);
        int col = cog * 128 + c16 * 8;
        int sblk = col >> 5, off = col & 31;
        *(uint4*)(zL + ((size_t)sblk * 32768 + row0 + row) * 32 + off) = v;
    }
}

// ---- all halo zeroing in one dispatch --------------------------------------
__global__ __launch_bounds__(256) void k_halo_all(
    unsigned short* a1, unsigned short* a2, unsigned short* a3,
    unsigned short* zq, unsigned short* d1)
{
    unsigned short* buf; int Hp, Wp, PS;
    switch (blockIdx.z) {
        case 0: buf = a1; Hp = 258; Wp = 258; PS = 64; break;
        case 1: buf = a2; Hp = 130; Wp = 130; PS = 64; break;
        case 2: buf = a3; Hp = 66; Wp = 66; PS = 64; break;
        case 3: buf = zq; Hp = 66; Wp = 66; PS = 512; break;
        default: buf = d1; Hp = 66; Wp = 66; PS = 64; break;
    }
    int per = 2 * Wp + 2 * (Hp - 2);
    int chunks = PS >> 3;
    int total = per * chunks;
    int n = blockIdx.y;
    for (int i = blockIdx.x * 256 + threadIdx.x; i < total; i += gridDim.x * 256) {
        int pix = i / chunks, c = i - pix * chunks;
        int h, w;
        if (pix < Wp) { h = 0; w = pix; }
        else if (pix < 2 * Wp) { h = Hp - 1; w = pix - Wp; }
        else { int q = pix - 2 * Wp; h = 1 + (q >> 1); w = (q & 1) ? (Wp - 1) : 0; }
        uint4 zz = {0, 0, 0, 0};
        *(uint4*)(buf + (((size_t)n * Hp + h) * Wp + w) * PS + c * 8) = zz;
    }
}

// ---- weight/codebook prep helpers ------------------------------------------
__device__ inline void prep_conv_dev(const float* __restrict__ w,
    unsigned short* __restrict__ o, int Cout, int Cin, int T, int CIC, int idx)
{
    if (idx >= Cout * Cin * T) return;
    int tap = idx % T; int r = idx / T; int ci = r % Cin; int co = r / Cin;
    int chunk = ci / CIC, cil = ci % CIC;
    int k = chunk * (T * CIC) + tap * CIC + cil;
    int s = k >> 5, g = (k >> 3) & 3, j = k & 7;
    o[((size_t)(s * 4 + g) * Cout + co) * 8 + j] = (unsigned short)bf16rne(w[idx]);
}

__device__ inline void prep_wT_dev(const float* __restrict__ w,
    unsigned short* __restrict__ o, int idx)
{
    if (idx >= 65536) return;
    int ci = idx & 63; int r = idx >> 6;
    int jw = r & 1; r >>= 1;
    int jh = r & 1; r >>= 1;
    int co = r & 63; r >>= 6;
    int pw = r & 1; int ph = (r >> 1) & 1;
    int kh = (1 - ph) + 2 * (1 - jh);
    int kw = (1 - pw) + 2 * (1 - jw);
    int k = (jh * 2 + jw) * 64 + ci;
    int s = k >> 5, g = (k >> 3) & 3, j = k & 7;
    o[(size_t)(ph * 2 + pw) * 16384 + ((size_t)(s * 4 + g) * 64 + co) * 8 + j] =
        (unsigned short)bf16rne(w[((ci * 64 + co) * 4 + kh) * 4 + kw]);
}

// ---- all weight/cb/cn2 prep in one dispatch: grid (1152, 8) ----------------
__global__ __launch_bounds__(256) void k_prep_all(
    const float* __restrict__ enc_w2, const float* __restrict__ enc_w3,
    const float* __restrict__ enc_w4, const float* __restrict__ dec_w1,
    const float* __restrict__ tw1, const float* __restrict__ tw2,
    const float* __restrict__ cb,
    unsigned short* __restrict__ wA2, unsigned short* __restrict__ wA3,
    unsigned short* __restrict__ wB1, unsigned short* __restrict__ wB2,
    unsigned short* __restrict__ wC1, unsigned short* __restrict__ wC2,
    unsigned short* __restrict__ cbF,
    float* __restrict__ cn2)
{
    int idx = blockIdx.x * 256 + threadIdx.x;
    switch (blockIdx.y) {
    case 0: prep_conv_dev(enc_w2, wA2, 64, 64, 16, 64, idx); break;
    case 1: prep_conv_dev(enc_w3, wA3, 64, 64, 16, 64, idx); break;
    case 2: prep_conv_dev(enc_w4, wB1, 512, 64, 9, 64, idx); break;
    case 3: prep_conv_dev(dec_w1, wB2, 64, 512, 9, 128, idx); break;
    case 4: prep_wT_dev(tw1, wC1, idx); break;
    case 5: prep_wT_dev(tw2, wC2, idx); break;
    case 6: {
        if (idx < 262144) {
            int c = idx & 511, k = idx >> 9;
            int cblk = k >> 7, kl = k & 127, s = c >> 5, g = (c >> 3) & 3, j = c & 7;
            size_t off = ((((size_t)cblk * 16 + s) * 4 + g) * 128 + kl) * 8 + j;
            cbF[off] = f16bits(cb[idx]);
        }
    } break;
    default: {
        int code = blockIdx.x * 4 + (threadIdx.x >> 6);
        if (code < 512) {
            int l = threadIdx.x & 63;
            float s = 0.f;
#pragma unroll
            for (int i = 0; i < 8; ++i) {
                float v = cb[code * 512 + l + i * 64];
                s = fmaf(v, v, s);
            }
#pragma unroll
            for (int off = 32; off > 0; off >>= 1) s += __shfl_xor(s, off);
            if (l == 0) cn2[code] = 0.5f * s;
        }
    } break;
    }
}

// ---- enc conv1: Cin=1, 4x4 s2 p1, ReLU -> bf16 NHWC padded ----------------
__global__ __launch_bounds__(256) void k_conv1(const float* __restrict__ x,
    const float* __restrict__ w, const float* __restrict__ b, unsigned short* __restrict__ out)
{
    __shared__ float ws[1024];
    __shared__ float bs[64];
    int t = threadIdx.x;
#pragma unroll
    for (int i = 0; i < 4; ++i) ws[t + 256 * i] = w[t + 256 * i];
    if (t < 64) bs[t] = b[t];
    __syncthreads();
    int oh = blockIdx.x;
    int n = blockIdx.y;
    int ow = t;
    const float* xn = x + (size_t)n * 262144;
    float xv[16];
#pragma unroll
    for (int kh = 0; kh < 4; ++kh) {
        int ih = 2 * oh - 1 + kh;
        bool rok = (unsigned)ih < 512u;
        int ihc = min(max(ih, 0), 511);
#pragma unroll
        for (int kw = 0; kw < 4; ++kw) {
            int iw = 2 * ow - 1 + kw;
            bool ok = rok && ((unsigned)iw < 512u);
            int iwc = min(max(iw, 0), 511);
            float v = xn[ihc * 512 + iwc];
            xv[kh * 4 + kw] = ok ? v : 0.f;
        }
    }
    unsigned short* on = out + (((size_t)n * 258 + oh + 1) * 258 + (ow + 1)) * 64;
    unsigned uo[32];
#pragma unroll
    for (int co2 = 0; co2 < 32; ++co2) {
        float a0 = bs[2 * co2], a1 = bs[2 * co2 + 1];
#pragma unroll
        for (int q = 0; q < 16; ++q) {
            a0 = fmaf(xv[q], ws[(2 * co2) * 16 + q], a0);
            a1 = fmaf(xv[q], ws[(2 * co2 + 1) * 16 + q], a1);
        }
        uo[co2] = pack2(fmaxf(a0, 0.f), fmaxf(a1, 0.f));
    }
#pragma unroll
    for (int i = 0; i < 8; ++i) {
        uint4 st = {uo[4 * i], uo[4 * i + 1], uo[4 * i + 2], uo[4 * i + 3]};
        *(uint4*)(on + i * 8) = st;
    }
}

__device__ inline bool better_sc(float av, int ai, float bv, int bi) {
    return av > bv || (av == bv && ai < bi);
}

// ---- VQ approx GEMM pass-1: fp16 single-term, top-2 per 128-code block -----
__global__ __launch_bounds__(256) void k_vqgemm(
    const unsigned short* __restrict__ zH, const unsigned short* __restrict__ cbF,
    const float* __restrict__ cn2, int* __restrict__ candI)
{
    __shared__ __align__(16) unsigned short shA[10240];
    __shared__ float tV[2][128][2];
    __shared__ int   tI[2][128][2];
    int t = threadIdx.x, lane = t & 63, wv = t >> 6;
    int wc = wv & 1, wr = wv >> 1;
    int m = lane & 15, g = lane >> 4;
    int L = blockIdx.x;
    int xcd = L & 7, kk = L >> 3;
    int cblk = kk & 3;
    int row0 = ((kk >> 2) + xcd * 32) * 128;

    f32x4_t acc[4][4];
#pragma unroll
    for (int a = 0; a < 4; ++a)
#pragma unroll
        for (int b = 0; b < 4; ++b) acc[a][b] = (f32x4_t){0.f, 0.f, 0.f, 0.f};

    const uint4* bF = (const uint4*)cbF + (size_t)cblk * 8192;

    for (int c = 0; c < 8; ++c) {
        if (c) __syncthreads();
        for (int q = t; q < 1280; q += 256) {
            int ss = q / 640, rest = q - ss * 640;
            int r = rest / 5, seg = rest - r * 5;
            int s = c * 2 + ss;
            gl_lds16(zH + ((size_t)s * 32768 + row0 + r) * 32 + (seg & 3) * 8,
                     shA + (size_t)q * 8);
        }
        __syncthreads();
#pragma unroll
        for (int ss = 0; ss < 2; ++ss) {
            int s = c * 2 + ss;
            Frag16 B[4];
#pragma unroll
            for (int ni = 0; ni < 4; ++ni)
                B[ni].u = bF[(s * 4 + g) * 128 + wc * 64 + ni * 16 + m];
#pragma unroll
            for (int mi = 0; mi < 4; ++mi) {
                Frag16 A;
                A.u = *(const uint4*)(shA + (size_t)(ss * 5120 + (wr * 64 + mi * 16 + m) * 40 + g * 8));
#pragma unroll
                for (int ni = 0; ni < 4; ++ni)
                    acc[mi][ni] = mfma16h(A.h, B[ni].h, acc[mi][ni]);
            }
        }
    }
    float c2[4];
#pragma unroll
    for (int ni = 0; ni < 4; ++ni) c2[ni] = cn2[cblk * 128 + wc * 64 + ni * 16 + m];
#pragma unroll
    for (int mi = 0; mi < 4; ++mi) {
#pragma unroll
        for (int r = 0; r < 4; ++r) {
            float v1 = -3e38f, v2 = -3e38f; int i1 = 0, i2 = 0;
#pragma unroll
            for (int ni = 0; ni < 4; ++ni) {
                float v = acc[mi][ni][r] - c2[ni];
                int ix = cblk * 128 + wc * 64 + ni * 16 + m;
                if (better_sc(v, ix, v1, i1)) { v2 = v1; i2 = i1; v1 = v; i1 = ix; }
                else if (better_sc(v, ix, v2, i2)) { v2 = v; i2 = ix; }
            }
#pragma unroll
            for (int off = 1; off < 16; off <<= 1) {
                float o1 = __shfl_xor(v1, off); int oi1 = __shfl_xor(i1, off);
                float o2 = __shfl_xor(v2, off); int oi2 = __shfl_xor(i2, off);
                if (better_sc(o1, oi1, v1, i1)) {
                    float nv2; int ni2;
                    if (better_sc(v1, i1, o2, oi2)) { nv2 = v1; ni2 = i1; }
                    else { nv2 = o2; ni2 = oi2; }
                    v1 = o1; i1 = oi1; v2 = nv2; i2 = ni2;
                } else if (better_sc(o1, oi1, v2, i2)) { v2 = o1; i2 = oi1; }
            }
            if (m == 0) {
                int row = wr * 64 + mi * 16 + g * 4 + r;
                tV[wc][row][0] = v1; tI[wc][row][0] = i1;
                tV[wc][row][1] = v2; tI[wc][row][1] = i2;
            }
        }
    }
    __syncthreads();
    if (t < 128) {
        float v1 = tV[0][t][0], v2 = tV[0][t][1];
        int i1 = tI[0][t][0], i2 = tI[0][t][1];
        float o1 = tV[1][t][0], o2 = tV[1][t][1];
        int oi1 = tI[1][t][0], oi2 = tI[1][t][1];
        if (better_sc(o1, oi1, v1, i1)) {
            float nv2; int ni2;
            if (better_sc(v1, i1, o2, oi2)) { nv2 = v1; ni2 = i1; }
            else { nv2 = o2; ni2 = oi2; }
            v1 = o1; i1 = oi1; v2 = nv2; i2 = ni2;
        } else if (better_sc(o1, oi1, v2, i2)) { v2 = o1; i2 = oi1; }
        candI[((size_t)cblk * 2 + 0) * 32768 + row0 + t] = i1;
        candI[((size_t)cblk * 2 + 1) * 32768 + row0 + t] = i2;
    }
}

// ---- VQ pass-2: wave-per-row exact fp32 rescore, no atomics ----------------
__global__ __launch_bounds__(256) void k_vqfinal(
    const unsigned short* __restrict__ zH, const unsigned short* __restrict__ zL,
    const float* __restrict__ cb, const int* __restrict__ candI,
    int* __restrict__ vidx, float* __restrict__ mind)
{
    int t = threadIdx.x, lane = t & 63, wv = t >> 6;
    int row = blockIdx.x * 4 + wv;
    size_t zoff = ((size_t)(lane >> 2) * 32768 + row) * 32 + (lane & 3) * 8;
    uint4 hu = *(const uint4*)(zH + zoff);
    uint4 lu = *(const uint4*)(zL + zoff);
    float z0 = f16lo(hu.x) + f16lo(lu.x);
    float z1 = f16hi(hu.x) + f16hi(lu.x);
    float z2 = f16lo(hu.y) + f16lo(lu.y);
    float z3 = f16hi(hu.y) + f16hi(lu.y);
    float z4 = f16lo(hu.z) + f16lo(lu.z);
    float z5 = f16hi(hu.z) + f16hi(lu.z);
    float z6 = f16lo(hu.w) + f16lo(lu.w);
    float z7 = f16hi(hu.w) + f16hi(lu.w);
    int mycand = (lane < 8) ? candI[(size_t)lane * 32768 + row] : 0;
    int cands[8];
    float d[8];
#pragma unroll
    for (int s = 0; s < 8; ++s) cands[s] = __shfl(mycand, s);
#pragma unroll
    for (int s = 0; s < 8; ++s) {
        const float* cr = cb + (size_t)cands[s] * 512 + lane * 8;
        float4 c0 = *(const float4*)cr;
        float4 c1 = *(const float4*)(cr + 4);
        float e, dd = 0.f;
        e = z0 - c0.x; dd = fmaf(e, e, dd);
        e = z1 - c0.y; dd = fmaf(e, e, dd);
        e = z2 - c0.z; dd = fmaf(e, e, dd);
        e = z3 - c0.w; dd = fmaf(e, e, dd);
        e = z4 - c1.x; dd = fmaf(e, e, dd);
        e = z5 - c1.y; dd = fmaf(e, e, dd);
        e = z6 - c1.z; dd = fmaf(e, e, dd);
        e = z7 - c1.w; dd = fmaf(e, e, dd);
        d[s] = dd;
    }
#pragma unroll
    for (int off = 1; off < 64; off <<= 1) {
#pragma unroll
        for (int s = 0; s < 8; ++s) d[s] += __shfl_xor(d[s], off);
    }
    float bd = d[0]; int bi_ = cands[0];
#pragma unroll
    for (int s = 1; s < 8; ++s) {
        if (d[s] < bd || (d[s] == bd && cands[s] < bi_)) { bd = d[s]; bi_ = cands[s]; }
    }
    if (lane == 0) { vidx[row] = bi_; mind[row] = bd; }
}

// ---- gather z_q -> padded NHWC bf16 [8,66,66,512] --------------------------
__global__ __launch_bounds__(256) void k_gather(const int* __restrict__ idx,
    const float* __restrict__ cb, unsigned short* __restrict__ zq)
{
    int t = threadIdx.x;
    int sp = blockIdx.x * 4 + (t >> 6);
    int lane = t & 63;
    int k = idx[sp];
    int n = sp >> 12, hw = sp & 4095, h = hw >> 6, w = hw & 63;
    const float* src = cb + (size_t)k * 512 + lane * 8;
    unsigned short* dst = zq + (((size_t)n * 66 + h + 1) * 66 + (w + 1)) * 512 + lane * 8;
    float4 v0 = *(const float4*)src, v1 = *(const float4*)(src + 4);
    uint4 st = {pack2(v0.x, v0.y), pack2(v0.z, v0.w), pack2(v1.x, v1.y), pack2(v1.z, v1.w)};
    *(uint4*)dst = st;
}

// ---- final conv-transpose 64 -> 1, sigmoid (LDS-staged, fp16 dot2) ---------
__global__ __launch_bounds__(256) void k_convt_final2(const unsigned short* __restrict__ xp,
    const float* __restrict__ w, const float* __restrict__ b, float* __restrict__ out)
{
    __shared__ __align__(16) unsigned short shx[3 * 1040 * 8];
    __shared__ __align__(16) unsigned wp[16][32];
    int t = threadIdx.x, lane = t & 63, wv = t >> 6;
    int bx = blockIdx.x, q = blockIdx.y, n = blockIdx.z;
    int colbase = bx * 128;
#pragma unroll
    for (int i = 0; i < 2; ++i) {
        int qq = t + i * 256;
        int tap = qq >> 5, c2 = qq & 31;
        wp[tap][c2] = pack2h(w[(2 * c2) * 16 + tap], w[(2 * c2 + 1) * 16 + tap]);
    }
    const unsigned short* an = xp + (size_t)n * 258 * 258 * 64;
    for (int u_ = wv; u_ < 51; u_ += 4) {
        int r = u_ / 17, seg = u_ % 17;
        int slot = seg * 64 + lane;
        if (slot < 1040) {
            int p = slot >> 3, uu = slot & 7;
            int su = (uu - p) & 7;
            int row = min(2 * q + r, 257);
            const unsigned short* gsrc = an + ((size_t)row * 258 + colbase + p) * 64 + su * 8;
            gl_lds16(gsrc, shx + ((size_t)(r * 1040 + slot)) * 8);
        }
    }
    __syncthreads();
    int ow = bx * 256 + t;
    int kwA = (ow + 1) & 1;
    int cA = ((ow + 1) >> 1) + 1 - colbase;
    int cB = cA - 1;
    float b0 = b[0];
    float acc0 = b0, acc1 = b0, acc2 = b0, acc3 = b0;
#pragma unroll
    for (int c8 = 0; c8 < 8; ++c8) {
        uint4 xr[3][2];
#pragma unroll
        for (int r = 0; r < 3; ++r) {
            xr[r][0] = *(const uint4*)(shx + (size_t)(r * 1040 + cB * 8 + ((c8 + cB) & 7)) * 8);
            xr[r][1] = *(const uint4*)(shx + (size_t)(r * 1040 + cA * 8 + ((c8 + cA) & 7)) * 8);
        }
        uint4 wA[4], wB[4];
#pragma unroll
        for (int kh = 0; kh < 4; ++kh) {
            wA[kh] = *(const uint4*)&wp[kh * 4 + kwA][c8 * 4];
            wB[kh] = *(const uint4*)&wp[kh * 4 + kwA + 2][c8 * 4];
        }
        acc0 = dot8(xr[1][1], wA[0], acc0); acc0 = dot8(xr[1][0], wB[0], acc0);
        acc0 = dot8(xr[0][1], wA[2], acc0); acc0 = dot8(xr[0][0], wB[2], acc0);
        acc1 = dot8(xr[1][1], wA[1], acc1); acc1 = dot8(xr[1][0], wB[1], acc1);
        acc1 = dot8(xr[0][1], wA[3], acc1); acc1 = dot8(xr[0][0], wB[3], acc1);
        acc2 = dot8(xr[2][1], wA[0], acc2); acc2 = dot8(xr[2][0], wB[0], acc2);
        acc2 = dot8(xr[1][1], wA[2], acc2); acc2 = dot8(xr[1][0], wB[2], acc2);
        acc3 = dot8(xr[2][1], wA[1], acc3); acc3 = dot8(xr[2][0], wB[1], acc3);
        acc3 = dot8(xr[1][1], wA[3], acc3); acc3 = dot8(xr[1][0], wB[3], acc3);
    }
    float accs[4] = {acc0, acc1, acc2, acc3};
    float* on = out + (size_t)n * 262144;
#pragma unroll
    for (int ro = 0; ro < 4; ++ro) {
        int oh = 4 * q - 1 + ro;
        if ((unsigned)oh < 512u)
            on[(size_t)oh * 512 + ow] = 1.0f / (1.0f + __expf(-accs[ro]));
    }
}

// ---- finalize loss: single-block reduction over mind[32768] ----------------
__global__ __launch_bounds__(256) void k_loss_final(const float* __restrict__ mind,
    float* __restrict__ out)
{
    __shared__ float redd[4];
    int t = threadIdx.x;
    float s = 0.f;
#pragma unroll 4
    for (int i = 0; i < 32; ++i) {
        float4 v = *(const float4*)(mind + i * 1024 + t * 4);
        s += v.x + v.y + v.z + v.w;
    }
#pragma unroll
    for (int off = 1; off < 64; off <<= 1) s += __shfl_xor(s, off);
    if ((t & 63) == 0) redd[t >> 6] = s;
    __syncthreads();
    if (t == 0)
        out[0] = 1.25f * (redd[0] + redd[1] + redd[2] + redd[3]) * (1.0f / 16777216.0f);
}

// ---------------------------------------------------------------------------
extern "C" void kernel_launch(void* const* d_in, const int* in_sizes, int n_in,
                              void* d_out, int out_size, void* d_ws, size_t ws_size,
                              hipStream_t stream)
{
    const float* x      = (const float*)d_in[0];
    const float* enc_w1 = (const float*)d_in[1];
    const float* enc_b1 = (const float*)d_in[2];
    const float* enc_w2 = (const float*)d_in[3];
    const float* enc_b2 = (const float*)d_in[4];
    const float* enc_w3 = (const float*)d_in[5];
    const float* enc_b3 = (const float*)d_in[6];
    const float* enc_w4 = (const float*)d_in[7];
    const float* enc_b4 = (const float*)d_in[8];
    const float* cb     = (const float*)d_in[9];
    const float* dec_w1 = (const float*)d_in[10];
    const float* dec_b1 = (const float*)d_in[11];
    const float* tw1    = (const float*)d_in[12];
    const float* tb1    = (const float*)d_in[13];
    const float* tw2    = (const float*)d_in[14];
    const float* tb2    = (const float*)d_in[15];
    const float* tw3    = (const float*)d_in[16];
    const float* tb3    = (const float*)d_in[17];
    float* out = (float*)d_out;

    unsigned short* a1 = (unsigned short*)d_ws;        // 8*258*258*64
    unsigned short* a2 = a1 + 34076672;                // 8*130*130*64
    unsigned short* a3 = a2 + 8652800;                 // 8*66*66*64
    unsigned short* zH = a3 + 2230272;                 // 16*32768*32 (fp16)
    unsigned short* zL = zH + 16777216;                // 16*32768*32 (fp16)
    unsigned short* zq = zL + 16777216;                // 8*66*66*512
    unsigned short* d1 = zq + 17842176;                // 8*66*66*64
    unsigned short* wA2 = d1 + 2230272;                // 65536
    unsigned short* wA3 = wA2 + 65536;
    unsigned short* wB1 = wA3 + 65536;                 // 294912
    unsigned short* wB2 = wB1 + 294912;                // 294912
    unsigned short* wC1 = wB2 + 294912;                // 65536
    unsigned short* wC2 = wC1 + 65536;                 // 65536
    unsigned short* cbF = wC2 + 65536;                 // 262144 (fp16 frag)
    float* cn2 = (float*)(cbF + 262144);               // 512
    int*   vidx = (int*)(cn2 + 512);                   // 32768
    int*   candI = vidx + 32768;                       // 8*32768
    float* mind = (float*)(candI + 262144);            // 32768

    // consolidated halos + preps
    k_halo_all<<<dim3(65, 8, 5), 256, 0, stream>>>(a1, a2, a3, zq, d1);
    k_prep_all<<<dim3(1152, 8), 256, 0, stream>>>(
        enc_w2, enc_w3, enc_w4, dec_w1, tw1, tw2, cb,
        wA2, wA3, wB1, wB2, wC1, wC2, cbF, cn2);

    // pipeline
    k_conv1<<<dim3(256, 8), 256, 0, stream>>>(x, enc_w1, enc_b1, a1);
    k_enc2w<<<dim3(128, 8), 256, 0, stream>>>(a1, wA2, enc_b2, a2);
    conv_mfma<4, 4, 2, 64, 32, 1, 0><<<dim3(2, 64, 8), 256, 0, stream>>>(
        a2, wA3, enc_b3, a3, 130, 130, 64, 1, 64, 1, 66, 66, 1);
    k_enc4<<<1024, 256, 0, stream>>>(a3, wB1, enc_b4, zH, zL);
    k_vqgemm<<<1024, 256, 0, stream>>>(zH, cbF, cn2, candI);
    k_vqfinal<<<8192, 256, 0, stream>>>(zH, zL, cb, candI, vidx, mind);
    k_gather<<<8192, 256, 0, stream>>>(vidx, cb, zq);
    conv_mfma<3, 3, 1, 128, 64, 2, 0><<<dim3(1, 64, 8), 256, 0, stream>>>(
        zq, wB2, dec_b1, d1, 66, 66, 512, 4, 64, 1, 66, 66, 1);
    k_convtf<0><<<dim3(1, 64, 8), 256, 0, stream>>>(d1, wC1, tb1, a2, 66, 66, 130, 130);
    k_convtf<3><<<dim3(2, 128, 8), 256, 0, stream>>>(a2, wC2, tb2, a1, 130, 130, 258, 258);
    k_convt_final2<<<dim3(2, 129, 8), 256, 0, stream>>>(a1, tw3, tb3, out);
    k_loss_final<<<1, 256, 0, stream>>>(mind, out + 2097152);
}

// Round 13
// 463.468 us; speedup vs baseline: 1.2477x; 1.0116x over previous
//
#include <hip/hip_runtime.h>
#include <math.h>

// ---------------------------------------------------------------------------
// VQ-VAE forward, bf16-MFMA. Round 13: vqgemm with 4-step staging chunks
// (barriers /4, LDS-aliased argmax scratch, 4 blocks/CU), gather fused into
// vqfinal.
// ---------------------------------------------------------------------------

typedef __bf16 bf16x8_t __attribute__((ext_vector_type(8)));
typedef _Float16 f16x8_t __attribute__((ext_vector_type(8)));
typedef float f32x4_t __attribute__((ext_vector_type(4)));
typedef _Float16 h2_t __attribute__((ext_vector_type(2)));

union FragU { uint4 u; bf16x8_t b; };
union Frag16 { uint4 u; f16x8_t h; };

__device__ inline f32x4_t mfma16(bf16x8_t a, bf16x8_t b, f32x4_t c) {
    return __builtin_amdgcn_mfma_f32_16x16x32_bf16(a, b, c, 0, 0, 0);
}
__device__ inline f32x4_t mfma16h(f16x8_t a, f16x8_t b, f32x4_t c) {
    return __builtin_amdgcn_mfma_f32_16x16x32_f16(a, b, c, 0, 0, 0);
}

__device__ inline void gl_lds16(const void* g, void* l) {
    __builtin_amdgcn_global_load_lds((const __attribute__((address_space(1))) void*)g,
                                     (__attribute__((address_space(3))) void*)l, 16, 0, 0);
}

__device__ inline unsigned bf16rne(float f) {
    unsigned u = __float_as_uint(f);
    u += 0x7FFFu + ((u >> 16) & 1u);
    return u >> 16;
}
__device__ inline unsigned pack2(float lo, float hi) {
    return bf16rne(lo) | (bf16rne(hi) << 16);
}
__device__ inline unsigned pack2h(float lo, float hi) {
    union { h2_t h; unsigned u; } r;
    r.h[0] = (_Float16)lo; r.h[1] = (_Float16)hi;
    return r.u;
}
__device__ inline unsigned short f16bits(float v) {
    union { _Float16 h; unsigned short s; } x; x.h = (_Float16)v; return x.s;
}
__device__ inline float f16lo(unsigned u) {
    union { unsigned u; h2_t h; } x; x.u = u; return (float)x.h[0];
}
__device__ inline float f16hi(unsigned u) {
    union { unsigned u; h2_t h; } x; x.u = u; return (float)x.h[1];
}
__device__ inline float bl(unsigned u) { return __uint_as_float(u << 16); }
__device__ inline float bh(unsigned u) { return __uint_as_float(u & 0xffff0000u); }

#if defined(__has_builtin)
#if __has_builtin(__builtin_amdgcn_fdot2)
#define HAS_FDOT2 1
#endif
#endif

__device__ inline float dot2h(unsigned x, unsigned w, float a) {
#ifdef HAS_FDOT2
    union { unsigned u; h2_t h; } ax, bw;
    ax.u = x; bw.u = w;
    return __builtin_amdgcn_fdot2(ax.h, bw.h, a, false);
#else
    union { unsigned u; _Float16 h[2]; } ax, bw;
    ax.u = x; bw.u = w;
    a = fmaf((float)ax.h[0], (float)bw.h[0], a);
    return fmaf((float)ax.h[1], (float)bw.h[1], a);
#endif
}
__device__ inline float dot8(uint4 x, uint4 w, float a) {
    a = dot2h(x.x, w.x, a); a = dot2h(x.y, w.y, a);
    a = dot2h(x.z, w.z, a); a = dot2h(x.w, w.w, a);
    return a;
}

// ---- generic implicit-GEMM conv (enc3, dec1) -------------------------------
template<int NR, int KW_, int SW, int CIC, int SPT, int NT, int OUTM>
__global__ __launch_bounds__(256) void conv_mfma(
    const unsigned short* __restrict__ in, const unsigned short* __restrict__ wp,
    const float* __restrict__ bias, void* __restrict__ outp,
    int Hp, int Wp, int PS, int nchunks, int Cout, int ncog,
    int Hpo, int Wpo, int relu)
{
    constexpr int W_ST = SW * (SPT - 1) + KW_;
    constexpr int SLOTS_PP = CIC / 8;
    constexpr int ROW_SLOTS = W_ST * SLOTS_PP;
    constexpr int SEGS = (ROW_SLOTS + 63) / 64;
    constexpr int KT = NR * KW_;
    constexpr int CSTEPS = CIC / 32;
    __shared__ __align__(16) unsigned short sh[NR * W_ST * CIC];

    int t = threadIdx.x, lane = t & 63, wv = t >> 6;
    int bx = blockIdx.x;
    int owt = bx;
    int ohg = blockIdx.y;
    int bz = blockIdx.z; int nb = bz / ncog; int cog = bz % ncog;
    int ow0 = owt * SPT;
    int row0 = SW * ohg;
    int col0 = SW * ow0;
    int coh = wv & 1;
    int sph = wv >> 1;
    int m = lane & 15, g = lane >> 4;

    f32x4_t acc[2][NT];
#pragma unroll
    for (int a = 0; a < 2; ++a)
#pragma unroll
        for (int u2 = 0; u2 < NT; ++u2) acc[a][u2] = (f32x4_t){0.f, 0.f, 0.f, 0.f};

    for (int ch = 0; ch < nchunks; ++ch) {
        if (ch) __syncthreads();
        for (int u_ = wv; u_ < NR * SEGS; u_ += 4) {
            int r = u_ / SEGS, seg = u_ - r * SEGS;
            int slot = seg * 64 + lane;
            int p = slot / SLOTS_PP;
            int uu = slot & (SLOTS_PP - 1);
            if (p < W_ST) {
                int su = (uu - (p & 7)) & (SLOTS_PP - 1);
                const unsigned short* gsrc = in +
                    (((size_t)nb * Hp + (row0 + r)) * Wp + (col0 + p)) * PS + ch * CIC + su * 8;
                unsigned short* ldst = sh + ((size_t)(r * ROW_SLOTS + seg * 64 + lane)) * 8;
                gl_lds16(gsrc, ldst);
            }
        }
        __syncthreads();
        int sbase = ch * (KT * CSTEPS);
#pragma unroll
        for (int tap = 0; tap < KT; ++tap) {
            const int r_l = tap / KW_, kwp = tap % KW_;
#pragma unroll
            for (int cs = 0; cs < CSTEPS; ++cs) {
                int s = sbase + tap * CSTEPS + cs;
                const uint4* wr = (const uint4*)wp + (size_t)(s * 4 + g) * Cout + cog * 64 + coh * 32 + m;
                FragU a0, a1;
                a0.u = wr[0];
                a1.u = wr[16];
#pragma unroll
                for (int u2 = 0; u2 < NT; ++u2) {
                    int sp_l = sph * (SPT / 2) + u2 * 16 + m;
                    int p = SW * sp_l + kwp;
                    int off = (cs * 32 + g * 8 + ((p & 7) << 3)) & (CIC - 1);
                    FragU bb;
                    bb.u = *(const uint4*)(sh + (size_t)(r_l * W_ST + p) * CIC + off);
                    acc[0][u2] = mfma16(a0.b, bb.b, acc[0][u2]);
                    acc[1][u2] = mfma16(a1.b, bb.b, acc[1][u2]);
                }
            }
        }
    }
#pragma unroll
    for (int a = 0; a < 2; ++a) {
        int co = cog * 64 + coh * 32 + a * 16 + g * 4;
        float4 bv = *(const float4*)(bias + co);
#pragma unroll
        for (int u2 = 0; u2 < NT; ++u2) {
            int ow = ow0 + sph * (SPT / 2) + u2 * 16 + m;
            float v0 = acc[a][u2][0] + bv.x;
            float v1 = acc[a][u2][1] + bv.y;
            float v2 = acc[a][u2][2] + bv.z;
            float v3 = acc[a][u2][3] + bv.w;
            if (relu) {
                v0 = fmaxf(v0, 0.f); v1 = fmaxf(v1, 0.f);
                v2 = fmaxf(v2, 0.f); v3 = fmaxf(v3, 0.f);
            }
            unsigned short* ob = (unsigned short*)outp;
            uint2 st;
            if constexpr (OUTM == 3) st = (uint2){pack2h(v0, v1), pack2h(v2, v3)};
            else                     st = (uint2){pack2(v0, v1), pack2(v2, v3)};
            *(uint2*)(ob + (((size_t)nb * Hpo + ohg + 1) * Wpo + (ow + 1)) * 64
                      + (coh * 32 + a * 16 + g * 4)) = st;
        }
    }
}

// ---- enc2: 4x4 s2 conv 64->64, full-row blocks (64co x 128sp) --------------
__global__ __launch_bounds__(256) void k_enc2w(
    const unsigned short* __restrict__ in, const unsigned short* __restrict__ wp,
    const float* __restrict__ bias, unsigned short* __restrict__ out)
{
    __shared__ __align__(16) unsigned short sh[16512];   // 258 px x 64 ch
    int t = threadIdx.x, lane = t & 63, wv = t >> 6;
    int m = lane & 15, g = lane >> 4;
    int ohg = blockIdx.x, n = blockIdx.y;

    f32x4_t acc[4][2];
#pragma unroll
    for (int a = 0; a < 4; ++a)
#pragma unroll
        for (int u2 = 0; u2 < 2; ++u2) acc[a][u2] = (f32x4_t){0.f, 0.f, 0.f, 0.f};

    const uint4* wp4 = (const uint4*)wp;
#pragma unroll
    for (int kh = 0; kh < 4; ++kh) {
        if (kh) __syncthreads();
        const unsigned short* rowp = in + ((size_t)(n * 258 + 2 * ohg + kh) * 258) * 64;
        for (int q = t; q < 2064; q += 256) {
            int p = q >> 3, uu = q & 7;
            int su = (uu - ((p >> 1) & 7)) & 7;
            gl_lds16(rowp + (size_t)p * 64 + su * 8, sh + (size_t)q * 8);
        }
        __syncthreads();
#pragma unroll
        for (int kwp = 0; kwp < 4; ++kwp) {
#pragma unroll
            for (int cs = 0; cs < 2; ++cs) {
                int s = (kh * 4 + kwp) * 2 + cs;
                const uint4* wr = wp4 + (size_t)(s * 4 + g) * 64 + m;
                FragU A[4];
#pragma unroll
                for (int a = 0; a < 4; ++a) A[a].u = wr[a * 16];
#pragma unroll
                for (int u2 = 0; u2 < 2; ++u2) {
                    int sp_l = wv * 32 + u2 * 16 + m;
                    int p = 2 * sp_l + kwp;
                    int rot = (sp_l + (kwp >> 1)) & 7;
                    int off = (cs * 32 + g * 8 + rot * 8) & 63;
                    FragU B;
                    B.u = *(const uint4*)(sh + (size_t)p * 64 + off);
#pragma unroll
                    for (int a = 0; a < 4; ++a)
                        acc[a][u2] = mfma16(A[a].b, B.b, acc[a][u2]);
                }
            }
        }
    }
#pragma unroll
    for (int a = 0; a < 4; ++a) {
        float4 bv = *(const float4*)(bias + a * 16 + g * 4);
#pragma unroll
        for (int u2 = 0; u2 < 2; ++u2) {
            int ow = wv * 32 + u2 * 16 + m;
            float v0 = fmaxf(acc[a][u2][0] + bv.x, 0.f);
            float v1 = fmaxf(acc[a][u2][1] + bv.y, 0.f);
            float v2 = fmaxf(acc[a][u2][2] + bv.z, 0.f);
            float v3 = fmaxf(acc[a][u2][3] + bv.w, 0.f);
            uint2 st = {pack2(v0, v1), pack2(v2, v3)};
            *(uint2*)(out + ((size_t)(n * 130 + ohg + 1) * 130 + ow + 1) * 64
                      + a * 16 + g * 4) = st;
        }
    }
}

// ---- fused conv-transpose 4x4 s2: all 4 phases in one block ---------------
template<int OUTM>
__global__ __launch_bounds__(256) void k_convtf(
    const unsigned short* __restrict__ in, const unsigned short* __restrict__ wp,
    const float* __restrict__ bias, unsigned short* __restrict__ out,
    int Hpi, int Wpi, int Hpo, int Wpo)
{
    __shared__ __align__(16) unsigned short sh[12672];   // 3 x 66 x 64
    int t = threadIdx.x, lane = t & 63, wv = t >> 6;
    int m = lane & 15, g = lane >> 4;
    int ph = wv >> 1, pw = wv & 1;
    int owt = blockIdx.x, ohg = blockIdx.y, n = blockIdx.z;
    int col0 = owt * 64;

    const unsigned short* an = in + ((size_t)(n * Hpi + ohg) * Wpi + col0) * 64;
    for (int q = t; q < 1584; q += 256) {
        int r = q / 528, rest = q - r * 528;
        int p = rest >> 3, uu = rest & 7;
        int su = (uu - (p & 7)) & 7;
        gl_lds16(an + ((size_t)r * Wpi + p) * 64 + su * 8, sh + (size_t)q * 8);
    }
    f32x4_t acc[4][4];
#pragma unroll
    for (int a = 0; a < 4; ++a)
#pragma unroll
        for (int u2 = 0; u2 < 4; ++u2) acc[a][u2] = (f32x4_t){0.f, 0.f, 0.f, 0.f};
    __syncthreads();

    const uint4* ws4 = (const uint4*)(wp + (size_t)(ph * 2 + pw) * 16384);
#pragma unroll
    for (int jh = 0; jh < 2; ++jh) {
#pragma unroll
        for (int jw = 0; jw < 2; ++jw) {
#pragma unroll
            for (int cs = 0; cs < 2; ++cs) {
                int s = (jh * 2 + jw) * 2 + cs;
                const uint4* wr = ws4 + (size_t)(s * 4 + g) * 64 + m;
                FragU A[4];
#pragma unroll
                for (int a = 0; a < 4; ++a) A[a].u = wr[a * 16];
                int r_l = ph + jh;
#pragma unroll
                for (int u2 = 0; u2 < 4; ++u2) {
                    int p = u2 * 16 + m + pw + jw;
                    int off = (cs * 32 + g * 8 + ((p & 7) << 3)) & 63;
                    FragU B;
                    B.u = *(const uint4*)(sh + (size_t)(r_l * 528 + p * 8) * 8 + off);
#pragma unroll
                    for (int a = 0; a < 4; ++a)
                        acc[a][u2] = mfma16(A[a].b, B.b, acc[a][u2]);
                }
            }
        }
    }
    int oho = 2 * ohg + ph;
#pragma unroll
    for (int a = 0; a < 4; ++a) {
        float4 bv = *(const float4*)(bias + a * 16 + g * 4);
#pragma unroll
        for (int u2 = 0; u2 < 4; ++u2) {
            int owo = 2 * (col0 + u2 * 16 + m) + pw;
            float v0 = fmaxf(acc[a][u2][0] + bv.x, 0.f);
            float v1 = fmaxf(acc[a][u2][1] + bv.y, 0.f);
            float v2 = fmaxf(acc[a][u2][2] + bv.z, 0.f);
            float v3 = fmaxf(acc[a][u2][3] + bv.w, 0.f);
            uint2 st;
            if constexpr (OUTM == 3) st = (uint2){pack2h(v0, v1), pack2h(v2, v3)};
            else                     st = (uint2){pack2(v0, v1), pack2(v2, v3)};
            *(uint2*)(out + ((size_t)(n * Hpo + oho + 1) * Wpo + owo + 1) * 64
                      + a * 16 + g * 4) = st;
        }
    }
}

// ---- enc4: 3x3 s1 conv 64->512, 128sp x 128co tiles ------------------------
__global__ __launch_bounds__(256) void k_enc4(
    const unsigned short* __restrict__ a3, const unsigned short* __restrict__ wp,
    const float* __restrict__ bias, unsigned short* __restrict__ zH,
    unsigned short* __restrict__ zL)
{
    __shared__ __align__(16) unsigned short sh[16896];
    int t = threadIdx.x, lane = t & 63, wv = t >> 6;
    int wc = wv & 1, wr = wv >> 1;
    int m = lane & 15, g = lane >> 4;
    int L = blockIdx.x;
    int xcd = L & 7, j = L >> 3;
    int cog = j & 3;
    int rt = (j >> 2) + xcd * 32;
    int row0 = rt * 128;
    int n = row0 >> 12;
    int oh0 = (row0 & 4095) >> 6;

    const unsigned short* an = a3 + ((size_t)(n * 66 + oh0) * 66) * 64;
    for (int seg = wv; seg < 33; seg += 4) {
        int slot = seg * 64 + lane;
        if (slot < 2112) {
            int r = slot / 528, rest = slot - r * 528;
            int p = rest >> 3, uu = rest & 7;
            int su = (uu - p) & 7;
            gl_lds16(an + ((size_t)(r * 66 + p)) * 64 + su * 8, sh + (size_t)slot * 8);
        }
    }
    f32x4_t acc[4][4];
#pragma unroll
    for (int a = 0; a < 4; ++a)
#pragma unroll
        for (int b = 0; b < 4; ++b) acc[a][b] = (f32x4_t){0.f, 0.f, 0.f, 0.f};
    __syncthreads();

#pragma unroll
    for (int tap = 0; tap < 9; ++tap) {
        const int kh = tap / 3, kwp = tap % 3;
#pragma unroll
        for (int cs = 0; cs < 2; ++cs) {
            int s = tap * 2 + cs;
            const uint4* wr4 = (const uint4*)wp + (size_t)(s * 4 + g) * 512 + cog * 128 + wc * 64 + m;
            FragU A[4];
#pragma unroll
            for (int ci = 0; ci < 4; ++ci) A[ci].u = wr4[ci * 16];
#pragma unroll
            for (int si = 0; si < 4; ++si) {
                int sp_l = wr * 64 + si * 16 + m;
                int r_l = (sp_l >> 6) + kh;
                int px = (sp_l & 63) + kwp;
                int off = (cs * 4 + g + px) & 7;
                FragU B;
                B.u = *(const uint4*)(sh + ((size_t)(r_l * 528 + px * 8 + off)) * 8);
#pragma unroll
                for (int ci = 0; ci < 4; ++ci)
                    acc[ci][si] = mfma16(A[ci].b, B.b, acc[ci][si]);
            }
        }
    }
    float4 bv[4];
#pragma unroll
    for (int ci = 0; ci < 4; ++ci)
        bv[ci] = *(const float4*)(bias + cog * 128 + wc * 64 + ci * 16 + g * 4);

    __syncthreads();
#pragma unroll
    for (int ci = 0; ci < 4; ++ci) {
#pragma unroll
        for (int si = 0; si < 4; ++si) {
            float v0 = acc[ci][si][0] + bv[ci].x;
            float v1 = acc[ci][si][1] + bv[ci].y;
            float v2 = acc[ci][si][2] + bv[ci].z;
            float v3 = acc[ci][si][3] + bv[ci].w;
            unsigned h0 = pack2h(v0, v1);
            unsigned h1 = pack2h(v2, v3);
            int row = wr * 64 + si * 16 + m;
            int col = wc * 64 + ci * 16 + g * 4;
            *(uint2*)(sh + (size_t)row * 132 + col) = (uint2){h0, h1};
        }
    }
    __syncthreads();
#pragma unroll
    for (int i = 0; i < 8; ++i) {
        int idx = i * 256 + t;
        int row = idx >> 4, c16 = idx & 15;
        uint4 v = *(const uint4*)(sh + (size_t)row * 132 + c16 * 8);
        int col = cog * 128 + c16 * 8;
        int sblk = col >> 5, off = col & 31;
        *(uint4*)(zH + ((size_t)sblk * 32768 + row0 + row) * 32 + off) = v;
    }
    __syncthreads();
#pragma unroll
    for (int ci = 0; ci < 4; ++ci) {
#pragma unroll
        for (int si = 0; si < 4; ++si) {
            float v0 = acc[ci][si][0] + bv[ci].x;
            float v1 = acc[ci][si][1] + bv[ci].y;
            float v2 = acc[ci][si][2] + bv[ci].z;
            float v3 = acc[ci][si][3] + bv[ci].w;
            unsigned h0 = pack2h(v0, v1);
            unsigned h1 = pack2h(v2, v3);
            unsigned l0 = pack2h(v0 - f16lo(h0), v1 - f16hi(h0));
            unsigned l1 = pack2h(v2 - f16lo(h1), v3 - f16hi(h1));
            int row = wr * 64 + si * 16 + m;
            int col = wc * 64 + ci * 16 + g * 4;
            *(uint2*)(sh + (size_t)row * 132 + col) = (uint2){l0, l1};
        }
    }
    __syncthreads();
#pragma unroll
    for (int i = 0; i < 8; ++i) {
        int idx = i * 256 + t;
        int row = idx >> 4, c16 = idx & 15;
        uint4 v = *(const uint4*)(sh + (size_t)row * 132 + c16 * 8);
        int col = cog * 128 + c16 * 8;
        int sblk = col >> 5, off = col & 31;
        *(uint4*)(zL + ((size_t)sblk * 32768 + row0 + row) * 32 + off) = v;
    }
}

// ---- all halo zeroing in one dispatch --------------------------------------
__global__ __launch_bounds__(256) void k_halo_all(
    unsigned short* a1, unsigned short* a2, unsigned short* a3,
    unsigned short* zq, unsigned short* d1)
{
    unsigned short* buf; int Hp, Wp, PS;
    switch (blockIdx.z) {
        case 0: buf = a1; Hp = 258; Wp = 258; PS = 64; break;
        case 1: buf = a2; Hp = 130; Wp = 130; PS = 64; break;
        case 2: buf = a3; Hp = 66; Wp = 66; PS = 64; break;
        case 3: buf = zq; Hp = 66; Wp = 66; PS = 512; break;
        default: buf = d1; Hp = 66; Wp = 66; PS = 64; break;
    }
    int per = 2 * Wp + 2 * (Hp - 2);
    int chunks = PS >> 3;
    int total = per * chunks;
    int n = blockIdx.y;
    for (int i = blockIdx.x * 256 + threadIdx.x; i < total; i += gridDim.x * 256) {
        int pix = i / chunks, c = i - pix * chunks;
        int h, w;
        if (pix < Wp) { h = 0; w = pix; }
        else if (pix < 2 * Wp) { h = Hp - 1; w = pix - Wp; }
        else { int q = pix - 2 * Wp; h = 1 + (q >> 1); w = (q & 1) ? (Wp - 1) : 0; }
        uint4 zz = {0, 0, 0, 0};
        *(uint4*)(buf + (((size_t)n * Hp + h) * Wp + w) * PS + c * 8) = zz;
    }
}

// ---- weight/codebook prep helpers ------------------------------------------
__device__ inline void prep_conv_dev(const float* __restrict__ w,
    unsigned short* __restrict__ o, int Cout, int Cin, int T, int CIC, int idx)
{
    if (idx >= Cout * Cin * T) return;
    int tap = idx % T; int r = idx / T; int ci = r % Cin; int co = r / Cin;
    int chunk = ci / CIC, cil = ci % CIC;
    int k = chunk * (T * CIC) + tap * CIC + cil;
    int s = k >> 5, g = (k >> 3) & 3, j = k & 7;
    o[((size_t)(s * 4 + g) * Cout + co) * 8 + j] = (unsigned short)bf16rne(w[idx]);
}

__device__ inline void prep_wT_dev(const float* __restrict__ w,
    unsigned short* __restrict__ o, int idx)
{
    if (idx >= 65536) return;
    int ci = idx & 63; int r = idx >> 6;
    int jw = r & 1; r >>= 1;
    int jh = r & 1; r >>= 1;
    int co = r & 63; r >>= 6;
    int pw = r & 1; int ph = (r >> 1) & 1;
    int kh = (1 - ph) + 2 * (1 - jh);
    int kw = (1 - pw) + 2 * (1 - jw);
    int k = (jh * 2 + jw) * 64 + ci;
    int s = k >> 5, g = (k >> 3) & 3, j = k & 7;
    o[(size_t)(ph * 2 + pw) * 16384 + ((size_t)(s * 4 + g) * 64 + co) * 8 + j] =
        (unsigned short)bf16rne(w[((ci * 64 + co) * 4 + kh) * 4 + kw]);
}

// ---- all weight/cb/cn2 prep in one dispatch: grid (1152, 8) ----------------
__global__ __launch_bounds__(256) void k_prep_all(
    const float* __restrict__ enc_w2, const float* __restrict__ enc_w3,
    const float* __restrict__ enc_w4, const float* __restrict__ dec_w1,
    const float* __restrict__ tw1, const float* __restrict__ tw2,
    const float* __restrict__ cb,
    unsigned short* __restrict__ wA2, unsigned short* __restrict__ wA3,
    unsigned short* __restrict__ wB1, unsigned short* __restrict__ wB2,
    unsigned short* __restrict__ wC1, unsigned short* __restrict__ wC2,
    unsigned short* __restrict__ cbF,
    float* __restrict__ cn2)
{
    int idx = blockIdx.x * 256 + threadIdx.x;
    switch (blockIdx.y) {
    case 0: prep_conv_dev(enc_w2, wA2, 64, 64, 16, 64, idx); break;
    case 1: prep_conv_dev(enc_w3, wA3, 64, 64, 16, 64, idx); break;
    case 2: prep_conv_dev(enc_w4, wB1, 512, 64, 9, 64, idx); break;
    case 3: prep_conv_dev(dec_w1, wB2, 64, 512, 9, 128, idx); break;
    case 4: prep_wT_dev(tw1, wC1, idx); break;
    case 5: prep_wT_dev(tw2, wC2, idx); break;
    case 6: {
        if (idx < 262144) {
            int c = idx & 511, k = idx >> 9;
            int cblk = k >> 7, kl = k & 127, s = c >> 5, g = (c >> 3) & 3, j = c & 7;
            size_t off = ((((size_t)cblk * 16 + s) * 4 + g) * 128 + kl) * 8 + j;
            cbF[off] = f16bits(cb[idx]);
        }
    } break;
    default: {
        int code = blockIdx.x * 4 + (threadIdx.x >> 6);
        if (code < 512) {
            int l = threadIdx.x & 63;
            float s = 0.f;
#pragma unroll
            for (int i = 0; i < 8; ++i) {
                float v = cb[code * 512 + l + i * 64];
                s = fmaf(v, v, s);
            }
#pragma unroll
            for (int off = 32; off > 0; off >>= 1) s += __shfl_xor(s, off);
            if (l == 0) cn2[code] = 0.5f * s;
        }
    } break;
    }
}

// ---- enc conv1: Cin=1, 4x4 s2 p1, ReLU -> bf16 NHWC padded ----------------
__global__ __launch_bounds__(256) void k_conv1(const float* __restrict__ x,
    const float* __restrict__ w, const float* __restrict__ b, unsigned short* __restrict__ out)
{
    __shared__ float ws[1024];
    __shared__ float bs[64];
    int t = threadIdx.x;
#pragma unroll
    for (int i = 0; i < 4; ++i) ws[t + 256 * i] = w[t + 256 * i];
    if (t < 64) bs[t] = b[t];
    __syncthreads();
    int oh = blockIdx.x;
    int n = blockIdx.y;
    int ow = t;
    const float* xn = x + (size_t)n * 262144;
    float xv[16];
#pragma unroll
    for (int kh = 0; kh < 4; ++kh) {
        int ih = 2 * oh - 1 + kh;
        bool rok = (unsigned)ih < 512u;
        int ihc = min(max(ih, 0), 511);
#pragma unroll
        for (int kw = 0; kw < 4; ++kw) {
            int iw = 2 * ow - 1 + kw;
            bool ok = rok && ((unsigned)iw < 512u);
            int iwc = min(max(iw, 0), 511);
            float v = xn[ihc * 512 + iwc];
            xv[kh * 4 + kw] = ok ? v : 0.f;
        }
    }
    unsigned short* on = out + (((size_t)n * 258 + oh + 1) * 258 + (ow + 1)) * 64;
    unsigned uo[32];
#pragma unroll
    for (int co2 = 0; co2 < 32; ++co2) {
        float a0 = bs[2 * co2], a1 = bs[2 * co2 + 1];
#pragma unroll
        for (int q = 0; q < 16; ++q) {
            a0 = fmaf(xv[q], ws[(2 * co2) * 16 + q], a0);
            a1 = fmaf(xv[q], ws[(2 * co2 + 1) * 16 + q], a1);
        }
        uo[co2] = pack2(fmaxf(a0, 0.f), fmaxf(a1, 0.f));
    }
#pragma unroll
    for (int i = 0; i < 8; ++i) {
        uint4 st = {uo[4 * i], uo[4 * i + 1], uo[4 * i + 2], uo[4 * i + 3]};
        *(uint4*)(on + i * 8) = st;
    }
}

__device__ inline bool better_sc(float av, int ai, float bv, int bi) {
    return av > bv || (av == bv && ai < bi);
}

// ---- VQ approx GEMM pass-1: fp16 single-term, top-2 per 128-code block -----
// 4 K-steps per staging chunk (4 barrier-pairs total); argmax scratch aliased
// into shA -> LDS = 40960 B exactly, 4 blocks/CU.
__global__ __launch_bounds__(256) void k_vqgemm(
    const unsigned short* __restrict__ zH, const unsigned short* __restrict__ cbF,
    const float* __restrict__ cn2, int* __restrict__ candI)
{
    __shared__ __align__(16) unsigned short shA[20480];  // 4 steps x 640 slots x 8
    int t = threadIdx.x, lane = t & 63, wv = t >> 6;
    int wc = wv & 1, wr = wv >> 1;
    int m = lane & 15, g = lane >> 4;
    int L = blockIdx.x;
    int xcd = L & 7, kk = L >> 3;
    int cblk = kk & 3;
    int row0 = ((kk >> 2) + xcd * 32) * 128;

    f32x4_t acc[4][4];
#pragma unroll
    for (int a = 0; a < 4; ++a)
#pragma unroll
        for (int b = 0; b < 4; ++b) acc[a][b] = (f32x4_t){0.f, 0.f, 0.f, 0.f};

    const uint4* bF = (const uint4*)cbF + (size_t)cblk * 8192;

    for (int c = 0; c < 4; ++c) {
        __syncthreads();
        for (int q = t; q < 2560; q += 256) {
            int ss = q / 640, rest = q - ss * 640;
            int r = rest / 5, seg = rest - r * 5;
            int s = c * 4 + ss;
            gl_lds16(zH + ((size_t)s * 32768 + row0 + r) * 32 + (seg & 3) * 8,
                     shA + (size_t)q * 8);
        }
        __syncthreads();
#pragma unroll
        for (int ss = 0; ss < 4; ++ss) {
            int s = c * 4 + ss;
            Frag16 B[4];
#pragma unroll
            for (int ni = 0; ni < 4; ++ni)
                B[ni].u = bF[(s * 4 + g) * 128 + wc * 64 + ni * 16 + m];
#pragma unroll
            for (int mi = 0; mi < 4; ++mi) {
                Frag16 A;
                A.u = *(const uint4*)(shA + (size_t)(ss * 5120 + (wr * 64 + mi * 16 + m) * 40 + g * 8));
#pragma unroll
                for (int ni = 0; ni < 4; ++ni)
                    acc[mi][ni] = mfma16h(A.h, B[ni].h, acc[mi][ni]);
            }
        }
    }
    // alias argmax scratch into shA (all K-loop LDS reads are done)
    __syncthreads();
    float* tV = (float*)shA;                 // [wc2][row128][cand2] = 1024 f
    int*   tI = (int*)(shA + 2048);          // byte off 4096, same shape
    float c2[4];
#pragma unroll
    for (int ni = 0; ni < 4; ++ni) c2[ni] = cn2[cblk * 128 + wc * 64 + ni * 16 + m];
#pragma unroll
    for (int mi = 0; mi < 4; ++mi) {
#pragma unroll
        for (int r = 0; r < 4; ++r) {
            float v1 = -3e38f, v2 = -3e38f; int i1 = 0, i2 = 0;
#pragma unroll
            for (int ni = 0; ni < 4; ++ni) {
                float v = acc[mi][ni][r] - c2[ni];
                int ix = cblk * 128 + wc * 64 + ni * 16 + m;
                if (better_sc(v, ix, v1, i1)) { v2 = v1; i2 = i1; v1 = v; i1 = ix; }
                else if (better_sc(v, ix, v2, i2)) { v2 = v; i2 = ix; }
            }
#pragma unroll
            for (int off = 1; off < 16; off <<= 1) {
                float o1 = __shfl_xor(v1, off); int oi1 = __shfl_xor(i1, off);
                float o2 = __shfl_xor(v2, off); int oi2 = __shfl_xor(i2, off);
                if (better_sc(o1, oi1, v1, i1)) {
                    float nv2; int ni2;
                    if (better_sc(v1, i1, o2, oi2)) { nv2 = v1; ni2 = i1; }
                    else { nv2 = o2; ni2 = oi2; }
                    v1 = o1; i1 = oi1; v2 = nv2; i2 = ni2;
                } else if (better_sc(o1, oi1, v2, i2)) { v2 = o1; i2 = oi1; }
            }
            if (m == 0) {
                int row = wr * 64 + mi * 16 + g * 4 + r;
                tV[(wc * 128 + row) * 2 + 0] = v1; tI[(wc * 128 + row) * 2 + 0] = i1;
                tV[(wc * 128 + row) * 2 + 1] = v2; tI[(wc * 128 + row) * 2 + 1] = i2;
            }
        }
    }
    __syncthreads();
    if (t < 128) {
        float v1 = tV[t * 2], v2 = tV[t * 2 + 1];
        int i1 = tI[t * 2], i2 = tI[t * 2 + 1];
        float o1 = tV[(128 + t) * 2], o2 = tV[(128 + t) * 2 + 1];
        int oi1 = tI[(128 + t) * 2], oi2 = tI[(128 + t) * 2 + 1];
        if (better_sc(o1, oi1, v1, i1)) {
            float nv2; int ni2;
            if (better_sc(v1, i1, o2, oi2)) { nv2 = v1; ni2 = i1; }
            else { nv2 = o2; ni2 = oi2; }
            v1 = o1; i1 = oi1; v2 = nv2; i2 = ni2;
        } else if (better_sc(o1, oi1, v2, i2)) { v2 = o1; i2 = oi1; }
        candI[((size_t)cblk * 2 + 0) * 32768 + row0 + t] = i1;
        candI[((size_t)cblk * 2 + 1) * 32768 + row0 + t] = i2;
    }
}

// ---- VQ pass-2: wave-per-row exact fp32 rescore + fused z_q gather ---------
__global__ __launch_bounds__(256) void k_vqfinal(
    const unsigned short* __restrict__ zH, const unsigned short* __restrict__ zL,
    const float* __restrict__ cb, const int* __restrict__ candI,
    unsigned short* __restrict__ zq, float* __restrict__ mind)
{
    int t = threadIdx.x, lane = t & 63, wv = t >> 6;
    int row = blockIdx.x * 4 + wv;
    size_t zoff = ((size_t)(lane >> 2) * 32768 + row) * 32 + (lane & 3) * 8;
    uint4 hu = *(const uint4*)(zH + zoff);
    uint4 lu = *(const uint4*)(zL + zoff);
    float z0 = f16lo(hu.x) + f16lo(lu.x);
    float z1 = f16hi(hu.x) + f16hi(lu.x);
    float z2 = f16lo(hu.y) + f16lo(lu.y);
    float z3 = f16hi(hu.y) + f16hi(lu.y);
    float z4 = f16lo(hu.z) + f16lo(lu.z);
    float z5 = f16hi(hu.z) + f16hi(lu.z);
    float z6 = f16lo(hu.w) + f16lo(lu.w);
    float z7 = f16hi(hu.w) + f16hi(lu.w);
    int mycand = (lane < 8) ? candI[(size_t)lane * 32768 + row] : 0;
    int cands[8];
    float d[8];
#pragma unroll
    for (int s = 0; s < 8; ++s) cands[s] = __shfl(mycand, s);
#pragma unroll
    for (int s = 0; s < 8; ++s) {
        const float* cr = cb + (size_t)cands[s] * 512 + lane * 8;
        float4 c0 = *(const float4*)cr;
        float4 c1 = *(const float4*)(cr + 4);
        float e, dd = 0.f;
        e = z0 - c0.x; dd = fmaf(e, e, dd);
        e = z1 - c0.y; dd = fmaf(e, e, dd);
        e = z2 - c0.z; dd = fmaf(e, e, dd);
        e = z3 - c0.w; dd = fmaf(e, e, dd);
        e = z4 - c1.x; dd = fmaf(e, e, dd);
        e = z5 - c1.y; dd = fmaf(e, e, dd);
        e = z6 - c1.z; dd = fmaf(e, e, dd);
        e = z7 - c1.w; dd = fmaf(e, e, dd);
        d[s] = dd;
    }
#pragma unroll
    for (int off = 1; off < 64; off <<= 1) {
#pragma unroll
        for (int s = 0; s < 8; ++s) d[s] += __shfl_xor(d[s], off);
    }
    float bd = d[0]; int bi_ = cands[0];
#pragma unroll
    for (int s = 1; s < 8; ++s) {
        if (d[s] < bd || (d[s] == bd && cands[s] < bi_)) { bd = d[s]; bi_ = cands[s]; }
    }
    // bd/bi_ identical across all 64 lanes -> fused z_q gather (bf16 NHWC halo)
    {
        int n = row >> 12, hw = row & 4095, h = hw >> 6, w = hw & 63;
        const float* src = cb + (size_t)bi_ * 512 + lane * 8;
        float4 v0 = *(const float4*)src, v1 = *(const float4*)(src + 4);
        uint4 st = {pack2(v0.x, v0.y), pack2(v0.z, v0.w),
                    pack2(v1.x, v1.y), pack2(v1.z, v1.w)};
        *(uint4*)(zq + (((size_t)n * 66 + h + 1) * 66 + (w + 1)) * 512 + lane * 8) = st;
    }
    if (lane == 0) mind[row] = bd;
}

// ---- final conv-transpose 64 -> 1, sigmoid (LDS-staged, fp16 dot2) ---------
__global__ __launch_bounds__(256) void k_convt_final2(const unsigned short* __restrict__ xp,
    const float* __restrict__ w, const float* __restrict__ b, float* __restrict__ out)
{
    __shared__ __align__(16) unsigned short shx[3 * 1040 * 8];
    __shared__ __align__(16) unsigned wp[16][32];
    int t = threadIdx.x, lane = t & 63, wv = t >> 6;
    int bx = blockIdx.x, q = blockIdx.y, n = blockIdx.z;
    int colbase = bx * 128;
#pragma unroll
    for (int i = 0; i < 2; ++i) {
        int qq = t + i * 256;
        int tap = qq >> 5, c2 = qq & 31;
        wp[tap][c2] = pack2h(w[(2 * c2) * 16 + tap], w[(2 * c2 + 1) * 16 + tap]);
    }
    const unsigned short* an = xp + (size_t)n * 258 * 258 * 64;
    for (int u_ = wv; u_ < 51; u_ += 4) {
        int r = u_ / 17, seg = u_ % 17;
        int slot = seg * 64 + lane;
        if (slot < 1040) {
            int p = slot >> 3, uu = slot & 7;
            int su = (uu - p) & 7;
            int row = min(2 * q + r, 257);
            const unsigned short* gsrc = an + ((size_t)row * 258 + colbase + p) * 64 + su * 8;
            gl_lds16(gsrc, shx + ((size_t)(r * 1040 + slot)) * 8);
        }
    }
    __syncthreads();
    int ow = bx * 256 + t;
    int kwA = (ow + 1) & 1;
    int cA = ((ow + 1) >> 1) + 1 - colbase;
    int cB = cA - 1;
    float b0 = b[0];
    float acc0 = b0, acc1 = b0, acc2 = b0, acc3 = b0;
#pragma unroll
    for (int c8 = 0; c8 < 8; ++c8) {
        uint4 xr[3][2];
#pragma unroll
        for (int r = 0; r < 3; ++r) {
            xr[r][0] = *(const uint4*)(shx + (size_t)(r * 1040 + cB * 8 + ((c8 + cB) & 7)) * 8);
            xr[r][1] = *(const uint4*)(shx + (size_t)(r * 1040 + cA * 8 + ((c8 + cA) & 7)) * 8);
        }
        uint4 wA[4], wB[4];
#pragma unroll
        for (int kh = 0; kh < 4; ++kh) {
            wA[kh] = *(const uint4*)&wp[kh * 4 + kwA][c8 * 4];
            wB[kh] = *(const uint4*)&wp[kh * 4 + kwA + 2][c8 * 4];
        }
        acc0 = dot8(xr[1][1], wA[0], acc0); acc0 = dot8(xr[1][0], wB[0], acc0);
        acc0 = dot8(xr[0][1], wA[2], acc0); acc0 = dot8(xr[0][0], wB[2], acc0);
        acc1 = dot8(xr[1][1], wA[1], acc1); acc1 = dot8(xr[1][0], wB[1], acc1);
        acc1 = dot8(xr[0][1], wA[3], acc1); acc1 = dot8(xr[0][0], wB[3], acc1);
        acc2 = dot8(xr[2][1], wA[0], acc2); acc2 = dot8(xr[2][0], wB[0], acc2);
        acc2 = dot8(xr[1][1], wA[2], acc2); acc2 = dot8(xr[1][0], wB[2], acc2);
        acc3 = dot8(xr[2][1], wA[1], acc3); acc3 = dot8(xr[2][0], wB[1], acc3);
        acc3 = dot8(xr[1][1], wA[3], acc3); acc3 = dot8(xr[1][0], wB[3], acc3);
    }
    float accs[4] = {acc0, acc1, acc2, acc3};
    float* on = out + (size_t)n * 262144;
#pragma unroll
    for (int ro = 0; ro < 4; ++ro) {
        int oh = 4 * q - 1 + ro;
        if ((unsigned)oh < 512u)
            on[(size_t)oh * 512 + ow] = 1.0f / (1.0f + __expf(-accs[ro]));
    }
}

// ---- finalize loss: single-block reduction over mind[32768] ----------------
__global__ __launch_bounds__(256) void k_loss_final(const float* __restrict__ mind,
    float* __restrict__ out)
{
    __shared__ float redd[4];
    int t = threadIdx.x;
    float s = 0.f;
#pragma unroll 4
    for (int i = 0; i < 32; ++i) {
        float4 v = *(const float4*)(mind + i * 1024 + t * 4);
        s += v.x + v.y + v.z + v.w;
    }
#pragma unroll
    for (int off = 1; off < 64; off <<= 1) s += __shfl_xor(s, off);
    if ((t & 63) == 0) redd[t >> 6] = s;
    __syncthreads();
    if (t == 0)
        out[0] = 1.25f * (redd[0] + redd[1] + redd[2] + redd[3]) * (1.0f / 16777216.0f);
}

// ---------------------------------------------------------------------------
extern "C" void kernel_launch(void* const* d_in, const int* in_sizes, int n_in,
                              void* d_out, int out_size, void* d_ws, size_t ws_size,
                              hipStream_t stream)
{
    const float* x      = (const float*)d_in[0];
    const float* enc_w1 = (const float*)d_in[1];
    const float* enc_b1 = (const float*)d_in[2];
    const float* enc_w2 = (const float*)d_in[3];
    const float* enc_b2 = (const float*)d_in[4];
    const float* enc_w3 = (const float*)d_in[5];
    const float* enc_b3 = (const float*)d_in[6];
    const float* enc_w4 = (const float*)d_in[7];
    const float* enc_b4 = (const float*)d_in[8];
    const float* cb     = (const float*)d_in[9];
    const float* dec_w1 = (const float*)d_in[10];
    const float* dec_b1 = (const float*)d_in[11];
    const float* tw1    = (const float*)d_in[12];
    const float* tb1    = (const float*)d_in[13];
    const float* tw2    = (const float*)d_in[14];
    const float* tb2    = (const float*)d_in[15];
    const float* tw3    = (const float*)d_in[16];
    const float* tb3    = (const float*)d_in[17];
    float* out = (float*)d_out;

    unsigned short* a1 = (unsigned short*)d_ws;        // 8*258*258*64
    unsigned short* a2 = a1 + 34076672;                // 8*130*130*64
    unsigned short* a3 = a2 + 8652800;                 // 8*66*66*64
    unsigned short* zH = a3 + 2230272;                 // 16*32768*32 (fp16)
    unsigned short* zL = zH + 16777216;                // 16*32768*32 (fp16)
    unsigned short* zq = zL + 16777216;                // 8*66*66*512
    unsigned short* d1 = zq + 17842176;                // 8*66*66*64
    unsigned short* wA2 = d1 + 2230272;                // 65536
    unsigned short* wA3 = wA2 + 65536;
    unsigned short* wB1 = wA3 + 65536;                 // 294912
    unsigned short* wB2 = wB1 + 294912;                // 294912
    unsigned short* wC1 = wB2 + 294912;                // 65536
    unsigned short* wC2 = wC1 + 65536;                 // 65536
    unsigned short* cbF = wC2 + 65536;                 // 262144 (fp16 frag)
    float* cn2 = (float*)(cbF + 262144);               // 512
    int*   candI = (int*)(cn2 + 512);                  // 8*32768
    float* mind = (float*)(candI + 262144);            // 32768

    // consolidated halos + preps
    k_halo_all<<<dim3(65, 8, 5), 256, 0, stream>>>(a1, a2, a3, zq, d1);
    k_prep_all<<<dim3(1152, 8), 256, 0, stream>>>(
        enc_w2, enc_w3, enc_w4, dec_w1, tw1, tw2, cb,
        wA2, wA3, wB1, wB2, wC1, wC2, cbF, cn2);

    // pipeline
    k_conv1<<<dim3(256, 8), 256, 0, stream>>>(x, enc_w1, enc_b1, a1);
    k_enc2w<<<dim3(128, 8), 256, 0, stream>>>(a1, wA2, enc_b2, a2);
    conv_mfma<4, 4, 2, 64, 32, 1, 0><<<dim3(2, 64, 8), 256, 0, stream>>>(
        a2, wA3, enc_b3, a3, 130, 130, 64, 1, 64, 1, 66, 66, 1);
    k_enc4<<<1024, 256, 0, stream>>>(a3, wB1, enc_b4, zH, zL);
    k_vqgemm<<<1024, 256, 0, stream>>>(zH, cbF, cn2, candI);
    k_vqfinal<<<8192, 256, 0, stream>>>(zH, zL, cb, candI, zq, mind);
    conv_mfma<3, 3, 1, 128, 64, 2, 0><<<dim3(1, 64, 8), 256, 0, stream>>>(
        zq, wB2, dec_b1, d1, 66, 66, 512, 4, 64, 1, 66, 66, 1);
    k_convtf<0><<<dim3(1, 64, 8), 256, 0, stream>>>(d1, wC1, tb1, a2, 66, 66, 130, 130);
    k_convtf<3><<<dim3(2, 128, 8), 256, 0, stream>>>(a2, wC2, tb2, a1, 130, 130, 258, 258);
    k_convt_final2<<<dim3(2, 129, 8), 256, 0, stream>>>(a1, tw3, tb3, out);
    k_loss_final<<<1, 256, 0, stream>>>(mind, out + 2097152);
}